// Round 2
// baseline (1470.809 us; speedup 1.0000x reference)
//
#include <hip/hip_runtime.h>
#include <math.h>

#define NN 100000
#define EE 1600000
#define GB 512
#define INC 96
#define HH 128
#define CC 100

// ---------------------------------------------------------------- init
__global__ __launch_bounds__(256) void k_init(float* __restrict__ deg, int* __restrict__ cnt, int n) {
    int i = blockIdx.x * 256 + threadIdx.x;
    if (i < n) { deg[i] = 1.0f; cnt[i] = 0; }   // self-loop weight 1 pre-seeded into degree
}

// ---------------------------------------------------------------- edge MLP: ew = softplus(relu(ea@W1+b1)@W2+b2)+1e-4
__global__ __launch_bounds__(256) void k_edge_mlp(
    const float* __restrict__ ea, const int* __restrict__ ei,
    const float* __restrict__ W1, const float* __restrict__ b1,
    const float* __restrict__ W2, const float* __restrict__ b2,
    float* __restrict__ ew, float* __restrict__ deg, int* __restrict__ cnt, int E)
{
    __shared__ __align__(16) float sW1t[1024];   // [j][k] = W1[k*128+j]
    __shared__ __align__(16) float2 sB[128];     // (b1[j], W2[j])
    int t = threadIdx.x;
    for (int lin = t; lin < 1024; lin += 256)
        sW1t[lin] = W1[(lin & 7) * 128 + (lin >> 3)];
    if (t < 128) sB[t] = make_float2(b1[t], W2[t]);
    __syncthreads();

    int base = blockIdx.x * 2048;
    float4 a0[8], a1[8];
    float acc[8];
    int   ec[8];
    bool  vv[8];
#pragma unroll
    for (int ii = 0; ii < 8; ++ii) {
        int e = base + t + ii * 256;
        vv[ii] = (e < E);
        int e2 = vv[ii] ? e : 0;
        ec[ii] = e2;
        a0[ii] = *(const float4*)&ea[(size_t)e2 * 8];
        a1[ii] = *(const float4*)&ea[(size_t)e2 * 8 + 4];
        acc[ii] = 0.0f;
    }
    for (int j = 0; j < 128; ++j) {
        float4 w0 = *(const float4*)&sW1t[j * 8];
        float4 w1 = *(const float4*)&sW1t[j * 8 + 4];
        float2 bw = sB[j];
#pragma unroll
        for (int ii = 0; ii < 8; ++ii) {
            float h = bw.x;
            h = fmaf(a0[ii].x, w0.x, h); h = fmaf(a0[ii].y, w0.y, h);
            h = fmaf(a0[ii].z, w0.z, h); h = fmaf(a0[ii].w, w0.w, h);
            h = fmaf(a1[ii].x, w1.x, h); h = fmaf(a1[ii].y, w1.y, h);
            h = fmaf(a1[ii].z, w1.z, h); h = fmaf(a1[ii].w, w1.w, h);
            h = fmaxf(h, 0.0f);
            acc[ii] = fmaf(h, bw.y, acc[ii]);
        }
    }
    float b2v = b2[0];
#pragma unroll
    for (int ii = 0; ii < 8; ++ii) {
        if (!vv[ii]) continue;
        float x = acc[ii] + b2v;
        float sp = (x > 20.0f) ? x : log1pf(expf(x));
        float w = sp + 1e-4f;
        ew[ec[ii]] = w;
        int c = ei[E + ec[ii]];          // col = edge_index[1][e]
        atomicAdd(&deg[c], w);
        atomicAdd(&cnt[c], 1);
    }
}

// ---------------------------------------------------------------- prefix scan (3-kernel) over cnt -> rowptr
__global__ __launch_bounds__(256) void k_scan1(const int* __restrict__ cnt, int* __restrict__ rp,
                                               int* __restrict__ bsum, int n) {
    __shared__ int s[256];
    int t = threadIdx.x, i = blockIdx.x * 256 + t;
    int v = (i < n) ? cnt[i] : 0;
    s[t] = v; __syncthreads();
    for (int o = 1; o < 256; o <<= 1) {
        int x = (t >= o) ? s[t - o] : 0;
        __syncthreads();
        s[t] += x;
        __syncthreads();
    }
    if (i < n) rp[i] = s[t] - v;          // exclusive within block
    if (t == 255) bsum[blockIdx.x] = s[255];
}

__global__ __launch_bounds__(512) void k_scan2(int* __restrict__ bsum, int nb) {
    __shared__ int s[512];
    int t = threadIdx.x;
    int v = (t < nb) ? bsum[t] : 0;
    s[t] = v; __syncthreads();
    for (int o = 1; o < 512; o <<= 1) {
        int x = (t >= o) ? s[t - o] : 0;
        __syncthreads();
        s[t] += x;
        __syncthreads();
    }
    if (t < nb) bsum[t] = s[t] - v;       // exclusive block offsets
}

__global__ __launch_bounds__(256) void k_scan3(int* __restrict__ rp, const int* __restrict__ bsum,
                                               int* __restrict__ cursor, int n, int total) {
    int i = blockIdx.x * 256 + threadIdx.x;
    if (i < n) {
        int r = rp[i] + bsum[blockIdx.x];
        rp[i] = r;
        cursor[i] = r;
    }
    if (i == 0) rp[n] = total;
}

// ---------------------------------------------------------------- dis = rsqrt(deg) in place
__global__ __launch_bounds__(256) void k_rsqrt(float* __restrict__ d, int n) {
    int i = blockIdx.x * 256 + threadIdx.x;
    if (i < n) d[i] = rsqrtf(d[i]);       // deg >= 1 always
}

// ---------------------------------------------------------------- scatter edges into CSR (by dst), precompute norm
__global__ __launch_bounds__(256) void k_fill(const int* __restrict__ ei, const float* __restrict__ ew,
                                              const float* __restrict__ dis, int* __restrict__ cursor,
                                              int* __restrict__ esrc, float* __restrict__ enorm, int E) {
    int e = blockIdx.x * 256 + threadIdx.x;
    if (e >= E) return;
    int r = ei[e], c = ei[E + e];
    float wn = dis[r] * ew[e] * dis[c];
    int p = atomicAdd(&cursor[c], 1);
    esrc[p] = r;
    enorm[p] = wn;
}

// ---------------------------------------------------------------- fp32 GEMM: C[M,128] = A[M,K]@B[K,128] (+bias)
__global__ __launch_bounds__(256) void k_gemm(const float* __restrict__ A, const float* __restrict__ B,
                                              const float* __restrict__ bias, float* __restrict__ C,
                                              int M, int K) {
    __shared__ __align__(16) float At[32][68];    // [k][m] transposed A tile
    __shared__ __align__(16) float Bs[32][132];   // [k][n]
    int tid = threadIdx.x;
    int tx = tid & 15, ty = tid >> 4;
    int m0 = blockIdx.x * 64;
    float acc[4][8];
#pragma unroll
    for (int r = 0; r < 4; ++r)
#pragma unroll
        for (int c = 0; c < 8; ++c) acc[r][c] = 0.0f;

    for (int kc = 0; kc < K; kc += 32) {
        {   // stage A (64 rows x 32 k), transposed into LDS
            int r = tid >> 3;             // 0..31
            int kk = (tid & 7) * 4;       // 0..28
#pragma unroll
            for (int h = 0; h < 2; ++h) {
                int row = m0 + r + h * 32;
                int rowc = row < M ? row : M - 1;
                float4 v = *(const float4*)&A[(size_t)rowc * K + kc + kk];
                At[kk + 0][r + h * 32] = v.x;
                At[kk + 1][r + h * 32] = v.y;
                At[kk + 2][r + h * 32] = v.z;
                At[kk + 3][r + h * 32] = v.w;
            }
        }
        {   // stage B (32 k x 128 n)
#pragma unroll
            for (int h = 0; h < 4; ++h) {
                int lin = tid * 4 + h * 1024;
                int kr = lin >> 7, cc = lin & 127;
                *(float4*)&Bs[kr][cc] = *(const float4*)&B[(size_t)(kc + kr) * 128 + cc];
            }
        }
        __syncthreads();
#pragma unroll
        for (int k = 0; k < 32; ++k) {
            float4 av = *(const float4*)&At[k][ty * 4];
            float4 b0 = *(const float4*)&Bs[k][tx * 4];
            float4 b1 = *(const float4*)&Bs[k][tx * 4 + 64];
            float ar[4] = {av.x, av.y, av.z, av.w};
            float bc[8] = {b0.x, b0.y, b0.z, b0.w, b1.x, b1.y, b1.z, b1.w};
#pragma unroll
            for (int r = 0; r < 4; ++r)
#pragma unroll
                for (int c = 0; c < 8; ++c)
                    acc[r][c] = fmaf(ar[r], bc[c], acc[r][c]);
        }
        __syncthreads();
    }
    float bv[8] = {0, 0, 0, 0, 0, 0, 0, 0};
    if (bias) {
        float4 t0 = *(const float4*)&bias[tx * 4];
        float4 t1 = *(const float4*)&bias[tx * 4 + 64];
        bv[0] = t0.x; bv[1] = t0.y; bv[2] = t0.z; bv[3] = t0.w;
        bv[4] = t1.x; bv[5] = t1.y; bv[6] = t1.z; bv[7] = t1.w;
    }
#pragma unroll
    for (int r = 0; r < 4; ++r) {
        int row = m0 + ty * 4 + r;
        if (row >= M) continue;
        float4 o0 = make_float4(acc[r][0] + bv[0], acc[r][1] + bv[1], acc[r][2] + bv[2], acc[r][3] + bv[3]);
        float4 o1 = make_float4(acc[r][4] + bv[4], acc[r][5] + bv[5], acc[r][6] + bv[6], acc[r][7] + bv[7]);
        *(float4*)&C[(size_t)row * 128 + tx * 4] = o0;
        *(float4*)&C[(size_t)row * 128 + tx * 4 + 64] = o1;
    }
}

// ---------------------------------------------------------------- aggregate + bias + LN + residual + relu + xsum
__global__ __launch_bounds__(256) void k_agg_ln(
    const float* __restrict__ hw, const float* __restrict__ dis,
    const int* __restrict__ rowptr, const int* __restrict__ esrc,
    const float* __restrict__ enorm,
    const float* __restrict__ cb, const float* __restrict__ gam,
    const float* __restrict__ bet, const float* __restrict__ res,
    float* __restrict__ out, float* __restrict__ xsum, int first, int n)
{
    int wv = threadIdx.x >> 6;
    int lane = threadIdx.x & 63;
    int i = blockIdx.x * 4 + wv;
    if (i >= n) return;
    float di = dis[i];
    float sn = di * di;                       // self-loop norm = 1/deg
    float2 acc = *(const float2*)&hw[(size_t)i * HH + lane * 2];
    acc.x *= sn; acc.y *= sn;
    int p1 = rowptr[i + 1];
    for (int p = rowptr[i]; p < p1; ++p) {
        int s = esrc[p];
        float wn = enorm[p];
        float2 v = *(const float2*)&hw[(size_t)s * HH + lane * 2];
        acc.x = fmaf(v.x, wn, acc.x);
        acc.y = fmaf(v.y, wn, acc.y);
    }
    float2 cbv = *(const float2*)&cb[lane * 2];
    acc.x += cbv.x; acc.y += cbv.y;
    // LayerNorm over 128 via wave reduction
    float s1 = acc.x + acc.y;
    float s2 = acc.x * acc.x + acc.y * acc.y;
#pragma unroll
    for (int o = 32; o > 0; o >>= 1) {
        s1 += __shfl_xor(s1, o, 64);
        s2 += __shfl_xor(s2, o, 64);
    }
    float mean = s1 * (1.0f / HH);
    float var = fmaxf(s2 * (1.0f / HH) - mean * mean, 0.0f);
    float rstd = rsqrtf(var + 1e-5f);
    float2 gv = *(const float2*)&gam[lane * 2];
    float2 bv = *(const float2*)&bet[lane * 2];
    float2 rv = *(const float2*)&res[(size_t)i * HH + lane * 2];
    float hx = fmaxf(fmaf(gv.x, (acc.x - mean) * rstd, bv.x) + rv.x, 0.0f);
    float hy = fmaxf(fmaf(gv.y, (acc.y - mean) * rstd, bv.y) + rv.y, 0.0f);
    *(float2*)&out[(size_t)i * HH + lane * 2] = make_float2(hx, hy);
    float2 xs;
    if (first) {
        xs = make_float2(hx, hy);
    } else {
        xs = *(const float2*)&xsum[(size_t)i * HH + lane * 2];
        xs.x += hx; xs.y += hy;
    }
    *(float2*)&xsum[(size_t)i * HH + lane * 2] = xs;
}

// ---------------------------------------------------------------- mean/max pool per graph (batch sorted)
__global__ __launch_bounds__(128) void k_pool(const float* __restrict__ xsum, const int* __restrict__ batch,
                                              float* __restrict__ gbuf, int n) {
    int g = blockIdx.x, t = threadIdx.x;
    int lo = 0, hi = n;
    while (lo < hi) { int m = (lo + hi) >> 1; if (batch[m] < g) lo = m + 1; else hi = m; }
    int start = lo;
    lo = start; hi = n;
    while (lo < hi) { int m = (lo + hi) >> 1; if (batch[m] < g + 1) lo = m + 1; else hi = m; }
    int end = lo;
    float sum = 0.0f, mx = -INFINITY;
    for (int nd = start; nd < end; ++nd) {
        float v = xsum[(size_t)nd * HH + t] * 0.25f;
        sum += v;
        mx = fmaxf(mx, v);
    }
    int cntg = end - start;
    float mean = sum / fmaxf((float)cntg, 1.0f);
    gbuf[(size_t)g * 256 + t] = mean;
    gbuf[(size_t)g * 256 + 128 + t] = (cntg > 0) ? mx : 0.0f;
}

// ---------------------------------------------------------------- head: relu(g@hW1+hb1)@hW2+hb2
__global__ __launch_bounds__(128) void k_head(const float* __restrict__ gbuf,
                                              const float* __restrict__ hW1, const float* __restrict__ hb1,
                                              const float* __restrict__ hW2, const float* __restrict__ hb2,
                                              float* __restrict__ out) {
    __shared__ __align__(16) float sg[256];
    __shared__ __align__(16) float sh[128];
    int g = blockIdx.x, t = threadIdx.x;
    sg[t] = gbuf[(size_t)g * 256 + t];
    sg[t + 128] = gbuf[(size_t)g * 256 + 128 + t];
    __syncthreads();
    float h = hb1[t];
    for (int k = 0; k < 256; ++k) h = fmaf(sg[k], hW1[(size_t)k * 128 + t], h);
    sh[t] = fmaxf(h, 0.0f);
    __syncthreads();
    if (t < 100) {
        float o = hb2[t];
        for (int k = 0; k < 128; ++k) o = fmaf(sh[k], hW2[(size_t)k * 100 + t], o);
        out[(size_t)g * 100 + t] = o;
    }
}

// ---------------------------------------------------------------- launch
extern "C" void kernel_launch(void* const* d_in, const int* in_sizes, int n_in,
                              void* d_out, int out_size, void* d_ws, size_t ws_size,
                              hipStream_t stream) {
    const float* x     = (const float*)d_in[0];
    const int*   ei    = (const int*)d_in[1];
    const int*   batch = (const int*)d_in[2];
    const float* ea    = (const float*)d_in[3];
    const float* eeW1  = (const float*)d_in[4];
    const float* eeb1  = (const float*)d_in[5];
    const float* eeW2  = (const float*)d_in[6];
    const float* eeb2  = (const float*)d_in[7];
    const float* W[4]  = {(const float*)d_in[8], (const float*)d_in[10], (const float*)d_in[12], (const float*)d_in[14]};
    const float* cb[4] = {(const float*)d_in[9], (const float*)d_in[11], (const float*)d_in[13], (const float*)d_in[15]};
    const float* gm[4] = {(const float*)d_in[16], (const float*)d_in[18], (const float*)d_in[20], (const float*)d_in[22]};
    const float* be[4] = {(const float*)d_in[17], (const float*)d_in[19], (const float*)d_in[21], (const float*)d_in[23]};
    const float* resW  = (const float*)d_in[24];
    const float* resb  = (const float*)d_in[25];
    const float* hW1   = (const float*)d_in[26];
    const float* hb1   = (const float*)d_in[27];
    const float* hW2   = (const float*)d_in[28];
    const float* hb2   = (const float*)d_in[29];
    float* out = (float*)d_out;

    // workspace layout (~226 MB total; res0 eliminated, cursor aliases cnt)
    char* w = (char*)d_ws;
    auto alloc = [&](size_t bytes) { void* p = w; w += (bytes + 255) & ~(size_t)255; return p; };
    float* ew     = (float*)alloc((size_t)EE * 4);        //  6.4 MB
    float* dis    = (float*)alloc((size_t)NN * 4);        //  0.4 MB (deg then rsqrt in place)
    int*   cnt    = (int*)  alloc((size_t)NN * 4);        //  0.4 MB (reused as cursor)
    int*   rowptr = (int*)  alloc((size_t)(NN + 1) * 4);  //  0.4 MB
    int*   bsum   = (int*)  alloc(2048);
    int*   esrc   = (int*)  alloc((size_t)EE * 4);        //  6.4 MB
    float* enorm  = (float*)alloc((size_t)EE * 4);        //  6.4 MB
    float* hw     = (float*)alloc((size_t)NN * HH * 4);   // 51.2 MB
    float* bufA   = (float*)alloc((size_t)NN * HH * 4);   // 51.2 MB
    float* bufB   = (float*)alloc((size_t)NN * HH * 4);   // 51.2 MB
    float* xsum   = (float*)alloc((size_t)NN * HH * 4);   // 51.2 MB
    float* gbuf   = (float*)alloc((size_t)GB * 256 * 4);  //  0.5 MB
    int*   cursor = cnt;   // cnt dead after scan1

    int nblkN = (NN + 255) / 256;            // 391
    int nblkE = (EE + 255) / 256;            // 6250
    int nblkEdgeMlp = (EE + 2047) / 2048;    // 782
    int nblkGemm = (NN + 63) / 64;           // 1563

    k_init<<<nblkN, 256, 0, stream>>>(dis, cnt, NN);
    k_edge_mlp<<<nblkEdgeMlp, 256, 0, stream>>>(ea, ei, eeW1, eeb1, eeW2, eeb2, ew, dis, cnt, EE);
    k_scan1<<<nblkN, 256, 0, stream>>>(cnt, rowptr, bsum, NN);
    k_scan2<<<1, 512, 0, stream>>>(bsum, nblkN);
    k_scan3<<<nblkN, 256, 0, stream>>>(rowptr, bsum, cursor, NN, EE);
    k_rsqrt<<<nblkN, 256, 0, stream>>>(dis, NN);
    k_fill<<<nblkE, 256, 0, stream>>>(ei, ew, dis, cursor, esrc, enorm, EE);

    // layer 0 (K=96): hw = x@W0; residual projection x@res_W+res_b into bufB (idle until L1 output)
    k_gemm<<<nblkGemm, 256, 0, stream>>>(x, W[0], nullptr, hw, NN, INC);
    k_gemm<<<nblkGemm, 256, 0, stream>>>(x, resW, resb, bufB, NN, INC);
    k_agg_ln<<<(NN + 3) / 4, 256, 0, stream>>>(hw, dis, rowptr, esrc, enorm,
                                               cb[0], gm[0], be[0], bufB, bufA, xsum, 1, NN);
    // layer 1
    k_gemm<<<nblkGemm, 256, 0, stream>>>(bufA, W[1], nullptr, hw, NN, HH);
    k_agg_ln<<<(NN + 3) / 4, 256, 0, stream>>>(hw, dis, rowptr, esrc, enorm,
                                               cb[1], gm[1], be[1], bufA, bufB, xsum, 0, NN);
    // layer 2
    k_gemm<<<nblkGemm, 256, 0, stream>>>(bufB, W[2], nullptr, hw, NN, HH);
    k_agg_ln<<<(NN + 3) / 4, 256, 0, stream>>>(hw, dis, rowptr, esrc, enorm,
                                               cb[2], gm[2], be[2], bufB, bufA, xsum, 0, NN);
    // layer 3
    k_gemm<<<nblkGemm, 256, 0, stream>>>(bufA, W[3], nullptr, hw, NN, HH);
    k_agg_ln<<<(NN + 3) / 4, 256, 0, stream>>>(hw, dis, rowptr, esrc, enorm,
                                               cb[3], gm[3], be[3], bufA, bufB, xsum, 0, NN);

    k_pool<<<GB, 128, 0, stream>>>(xsum, batch, gbuf, NN);
    k_head<<<GB, 128, 0, stream>>>(gbuf, hW1, hb1, hW2, hb2, out);
}

// Round 3
// 1398.448 us; speedup vs baseline: 1.0517x; 1.0517x over previous
//
#include <hip/hip_runtime.h>
#include <math.h>

#define NN 100000
#define EE 1600000
#define GB 512
#define INC 96
#define HH 128
#define CC 100

typedef __bf16 bf16x8 __attribute__((ext_vector_type(8)));
typedef __bf16 bf16x2 __attribute__((ext_vector_type(2)));
typedef float f32x4 __attribute__((ext_vector_type(4)));

// ---------------------------------------------------------------- init
__global__ __launch_bounds__(256) void k_init(float* __restrict__ deg, int* __restrict__ cnt, int n) {
    int i = blockIdx.x * 256 + threadIdx.x;
    if (i < n) { deg[i] = 1.0f; cnt[i] = 0; }   // self-loop weight 1 pre-seeded into degree
}

// ---------------------------------------------------------------- cast x (N*INC fp32) -> bf16
__global__ __launch_bounds__(256) void k_cast(const float* __restrict__ src, __bf16* __restrict__ dst, int n4) {
    int i = blockIdx.x * 256 + threadIdx.x;
    if (i >= n4) return;
    float4 v = *(const float4*)&src[(size_t)i * 4];
    bf16x2 a, b;
    a.x = (__bf16)v.x; a.y = (__bf16)v.y;
    b.x = (__bf16)v.z; b.y = (__bf16)v.w;
    *(bf16x2*)&dst[(size_t)i * 4]     = a;
    *(bf16x2*)&dst[(size_t)i * 4 + 2] = b;
}

// ---------------------------------------------------------------- edge MLP: ew = softplus(relu(ea@W1+b1)@W2+b2)+1e-4
__global__ __launch_bounds__(256) void k_edge_mlp(
    const float* __restrict__ ea, const int* __restrict__ ei,
    const float* __restrict__ W1, const float* __restrict__ b1,
    const float* __restrict__ W2, const float* __restrict__ b2,
    float* __restrict__ ew, float* __restrict__ deg, int* __restrict__ cnt, int E)
{
    __shared__ __align__(16) float sW1t[1024];   // [j][k] = W1[k*128+j]
    __shared__ __align__(16) float2 sB[128];     // (b1[j], W2[j])
    int t = threadIdx.x;
    for (int lin = t; lin < 1024; lin += 256)
        sW1t[lin] = W1[(lin & 7) * 128 + (lin >> 3)];
    if (t < 128) sB[t] = make_float2(b1[t], W2[t]);
    __syncthreads();

    int base = blockIdx.x * 2048;
    float4 a0[8], a1[8];
    float acc[8];
    int   ec[8];
    bool  vv[8];
#pragma unroll
    for (int ii = 0; ii < 8; ++ii) {
        int e = base + t + ii * 256;
        vv[ii] = (e < E);
        int e2 = vv[ii] ? e : 0;
        ec[ii] = e2;
        a0[ii] = *(const float4*)&ea[(size_t)e2 * 8];
        a1[ii] = *(const float4*)&ea[(size_t)e2 * 8 + 4];
        acc[ii] = 0.0f;
    }
    for (int j = 0; j < 128; ++j) {
        float4 w0 = *(const float4*)&sW1t[j * 8];
        float4 w1 = *(const float4*)&sW1t[j * 8 + 4];
        float2 bw = sB[j];
#pragma unroll
        for (int ii = 0; ii < 8; ++ii) {
            float h = bw.x;
            h = fmaf(a0[ii].x, w0.x, h); h = fmaf(a0[ii].y, w0.y, h);
            h = fmaf(a0[ii].z, w0.z, h); h = fmaf(a0[ii].w, w0.w, h);
            h = fmaf(a1[ii].x, w1.x, h); h = fmaf(a1[ii].y, w1.y, h);
            h = fmaf(a1[ii].z, w1.z, h); h = fmaf(a1[ii].w, w1.w, h);
            h = fmaxf(h, 0.0f);
            acc[ii] = fmaf(h, bw.y, acc[ii]);
        }
    }
    float b2v = b2[0];
#pragma unroll
    for (int ii = 0; ii < 8; ++ii) {
        if (!vv[ii]) continue;
        float x = acc[ii] + b2v;
        float sp = (x > 20.0f) ? x : log1pf(expf(x));
        float w = sp + 1e-4f;
        ew[ec[ii]] = w;
        int c = ei[E + ec[ii]];          // col = edge_index[1][e]
        atomicAdd(&deg[c], w);
        atomicAdd(&cnt[c], 1);
    }
}

// ---------------------------------------------------------------- prefix scan (3-kernel) over cnt -> rowptr
__global__ __launch_bounds__(256) void k_scan1(const int* __restrict__ cnt, int* __restrict__ rp,
                                               int* __restrict__ bsum, int n) {
    __shared__ int s[256];
    int t = threadIdx.x, i = blockIdx.x * 256 + t;
    int v = (i < n) ? cnt[i] : 0;
    s[t] = v; __syncthreads();
    for (int o = 1; o < 256; o <<= 1) {
        int x = (t >= o) ? s[t - o] : 0;
        __syncthreads();
        s[t] += x;
        __syncthreads();
    }
    if (i < n) rp[i] = s[t] - v;          // exclusive within block
    if (t == 255) bsum[blockIdx.x] = s[255];
}

__global__ __launch_bounds__(512) void k_scan2(int* __restrict__ bsum, int nb) {
    __shared__ int s[512];
    int t = threadIdx.x;
    int v = (t < nb) ? bsum[t] : 0;
    s[t] = v; __syncthreads();
    for (int o = 1; o < 512; o <<= 1) {
        int x = (t >= o) ? s[t - o] : 0;
        __syncthreads();
        s[t] += x;
        __syncthreads();
    }
    if (t < nb) bsum[t] = s[t] - v;       // exclusive block offsets
}

__global__ __launch_bounds__(256) void k_scan3(int* __restrict__ rp, const int* __restrict__ bsum,
                                               int* __restrict__ cursor, int n, int total) {
    int i = blockIdx.x * 256 + threadIdx.x;
    if (i < n) {
        int r = rp[i] + bsum[blockIdx.x];
        rp[i] = r;
        cursor[i] = r;
    }
    if (i == 0) rp[n] = total;
}

// ---------------------------------------------------------------- dis = rsqrt(deg) in place
__global__ __launch_bounds__(256) void k_rsqrt(float* __restrict__ d, int n) {
    int i = blockIdx.x * 256 + threadIdx.x;
    if (i < n) d[i] = rsqrtf(d[i]);       // deg >= 1 always
}

// ---------------------------------------------------------------- scatter edges into CSR (by dst), precompute norm
__global__ __launch_bounds__(256) void k_fill(const int* __restrict__ ei, const float* __restrict__ ew,
                                              const float* __restrict__ dis, int* __restrict__ cursor,
                                              int* __restrict__ esrc, float* __restrict__ enorm, int E) {
    int e = blockIdx.x * 256 + threadIdx.x;
    if (e >= E) return;
    int r = ei[e], c = ei[E + e];
    float wn = dis[r] * ew[e] * dis[c];
    int p = atomicAdd(&cursor[c], 1);
    esrc[p] = r;
    enorm[p] = wn;
}

// ---------------------------------------------------------------- bf16 MFMA GEMM: C[M,128] = A[M,K]@B[K,128] (+bias)
// 64x128 tile / 256-thread block (4 waves). Whole B staged transposed in LDS (one barrier).
// mfma_f32_16x16x32_bf16 layouts (verified m89/m91): A-frag A[m=lane&15][k=quad*8+j],
// B-frag B[k=quad*8+j][n=lane&15], C/D col=lane&15 row=quad*4+reg.
#define LSTR 136   // padded LDS row stride (elems): +8 keeps 16B alignment, breaks pow2 banks
__global__ __launch_bounds__(256) void k_gemm_bf16(
    const __bf16* __restrict__ A, const float* __restrict__ B,
    const float* __restrict__ bias, __bf16* __restrict__ C, int M, int K)
{
    __shared__ __align__(16) __bf16 sA[64 * LSTR];
    __shared__ __align__(16) __bf16 sBt[128 * LSTR];
    int tid = threadIdx.x;
    int m0 = blockIdx.x * 64;
    // stage A tile (64 x K bf16), direct copy 16B chunks
    int CHK = K >> 3;                       // 8-elem chunks per row (12 or 16)
    for (int c = tid; c < 64 * CHK; c += 256) {
        int row = c / CHK, kk = (c - row * CHK) * 8;
        int rowg = m0 + row; if (rowg >= M) rowg = M - 1;
        uint4 v = *(const uint4*)&A[(size_t)rowg * K + kk];
        *(uint4*)&sA[row * LSTR + kk] = v;
    }
    // stage B transposed (Bt[n][k]), fp32->bf16
    for (int lin = tid * 4; lin < K * 128; lin += 1024) {
        int k = lin >> 7, n = lin & 127;
        float4 v = *(const float4*)&B[lin];
        sBt[(n + 0) * LSTR + k] = (__bf16)v.x;
        sBt[(n + 1) * LSTR + k] = (__bf16)v.y;
        sBt[(n + 2) * LSTR + k] = (__bf16)v.z;
        sBt[(n + 3) * LSTR + k] = (__bf16)v.w;
    }
    __syncthreads();

    int wv = tid >> 6, lane = tid & 63;
    int ln15 = lane & 15, quad = lane >> 4;
    int n0 = wv * 32;
    f32x4 acc[4][2];
#pragma unroll
    for (int mt = 0; mt < 4; ++mt)
#pragma unroll
        for (int nt = 0; nt < 2; ++nt) acc[mt][nt] = (f32x4){0.f, 0.f, 0.f, 0.f};

    for (int kc = 0; kc < K; kc += 32) {
        bf16x8 af[4], bf[2];
#pragma unroll
        for (int mt = 0; mt < 4; ++mt)
            af[mt] = *(const bf16x8*)&sA[(mt * 16 + ln15) * LSTR + kc + quad * 8];
#pragma unroll
        for (int nt = 0; nt < 2; ++nt)
            bf[nt] = *(const bf16x8*)&sBt[(n0 + nt * 16 + ln15) * LSTR + kc + quad * 8];
#pragma unroll
        for (int mt = 0; mt < 4; ++mt)
#pragma unroll
            for (int nt = 0; nt < 2; ++nt)
                acc[mt][nt] = __builtin_amdgcn_mfma_f32_16x16x32_bf16(af[mt], bf[nt], acc[mt][nt], 0, 0, 0);
    }
#pragma unroll
    for (int nt = 0; nt < 2; ++nt) {
        int col = n0 + nt * 16 + ln15;
        float bv = bias ? bias[col] : 0.0f;
#pragma unroll
        for (int mt = 0; mt < 4; ++mt) {
#pragma unroll
            for (int r = 0; r < 4; ++r) {
                int row = m0 + mt * 16 + quad * 4 + r;
                if (row < M) C[(size_t)row * 128 + col] = (__bf16)(acc[mt][nt][r] + bv);
            }
        }
    }
}

// ---------------------------------------------------------------- aggregate + bias + LN + residual + relu + xsum
// one wave per node; hw/res/out in bf16, math + xsum in fp32
__global__ __launch_bounds__(256) void k_agg_ln(
    const __bf16* __restrict__ hw, const float* __restrict__ dis,
    const int* __restrict__ rowptr, const int* __restrict__ esrc,
    const float* __restrict__ enorm,
    const float* __restrict__ cb, const float* __restrict__ gam,
    const float* __restrict__ bet, const __bf16* __restrict__ res,
    __bf16* __restrict__ out, float* __restrict__ xsum, int first, int n)
{
    int wv = threadIdx.x >> 6;
    int lane = threadIdx.x & 63;
    int i = blockIdx.x * 4 + wv;
    if (i >= n) return;
    float di = dis[i];
    float sn = di * di;                       // self-loop norm = 1/deg
    bf16x2 h2 = *(const bf16x2*)&hw[(size_t)i * HH + lane * 2];
    float2 acc = make_float2((float)h2.x * sn, (float)h2.y * sn);
    int p1 = rowptr[i + 1];
    for (int p = rowptr[i]; p < p1; ++p) {
        int s = esrc[p];
        float wn = enorm[p];
        bf16x2 v2 = *(const bf16x2*)&hw[(size_t)s * HH + lane * 2];
        acc.x = fmaf((float)v2.x, wn, acc.x);
        acc.y = fmaf((float)v2.y, wn, acc.y);
    }
    float2 cbv = *(const float2*)&cb[lane * 2];
    acc.x += cbv.x; acc.y += cbv.y;
    // LayerNorm over 128 via wave reduction
    float s1 = acc.x + acc.y;
    float s2 = acc.x * acc.x + acc.y * acc.y;
#pragma unroll
    for (int o = 32; o > 0; o >>= 1) {
        s1 += __shfl_xor(s1, o, 64);
        s2 += __shfl_xor(s2, o, 64);
    }
    float mean = s1 * (1.0f / HH);
    float var = fmaxf(s2 * (1.0f / HH) - mean * mean, 0.0f);
    float rstd = rsqrtf(var + 1e-5f);
    float2 gv = *(const float2*)&gam[lane * 2];
    float2 bv = *(const float2*)&bet[lane * 2];
    bf16x2 r2 = *(const bf16x2*)&res[(size_t)i * HH + lane * 2];
    float hx = fmaxf(fmaf(gv.x, (acc.x - mean) * rstd, bv.x) + (float)r2.x, 0.0f);
    float hy = fmaxf(fmaf(gv.y, (acc.y - mean) * rstd, bv.y) + (float)r2.y, 0.0f);
    bf16x2 o2; o2.x = (__bf16)hx; o2.y = (__bf16)hy;
    *(bf16x2*)&out[(size_t)i * HH + lane * 2] = o2;
    float2 xs;
    if (first) {
        xs = make_float2(hx, hy);
    } else {
        xs = *(const float2*)&xsum[(size_t)i * HH + lane * 2];
        xs.x += hx; xs.y += hy;
    }
    *(float2*)&xsum[(size_t)i * HH + lane * 2] = xs;
}

// ---------------------------------------------------------------- mean/max pool per graph (batch sorted)
__global__ __launch_bounds__(128) void k_pool(const float* __restrict__ xsum, const int* __restrict__ batch,
                                              float* __restrict__ gbuf, int n) {
    int g = blockIdx.x, t = threadIdx.x;
    int lo = 0, hi = n;
    while (lo < hi) { int m = (lo + hi) >> 1; if (batch[m] < g) lo = m + 1; else hi = m; }
    int start = lo;
    lo = start; hi = n;
    while (lo < hi) { int m = (lo + hi) >> 1; if (batch[m] < g + 1) lo = m + 1; else hi = m; }
    int end = lo;
    float sum = 0.0f, mx = -INFINITY;
    for (int nd = start; nd < end; ++nd) {
        float v = xsum[(size_t)nd * HH + t] * 0.25f;
        sum += v;
        mx = fmaxf(mx, v);
    }
    int cntg = end - start;
    float mean = sum / fmaxf((float)cntg, 1.0f);
    gbuf[(size_t)g * 256 + t] = mean;
    gbuf[(size_t)g * 256 + 128 + t] = (cntg > 0) ? mx : 0.0f;
}

// ---------------------------------------------------------------- head: relu(g@hW1+hb1)@hW2+hb2
__global__ __launch_bounds__(128) void k_head(const float* __restrict__ gbuf,
                                              const float* __restrict__ hW1, const float* __restrict__ hb1,
                                              const float* __restrict__ hW2, const float* __restrict__ hb2,
                                              float* __restrict__ out) {
    __shared__ __align__(16) float sg[256];
    __shared__ __align__(16) float sh[128];
    int g = blockIdx.x, t = threadIdx.x;
    sg[t] = gbuf[(size_t)g * 256 + t];
    sg[t + 128] = gbuf[(size_t)g * 256 + 128 + t];
    __syncthreads();
    float h = hb1[t];
    for (int k = 0; k < 256; ++k) h = fmaf(sg[k], hW1[(size_t)k * 128 + t], h);
    sh[t] = fmaxf(h, 0.0f);
    __syncthreads();
    if (t < 100) {
        float o = hb2[t];
        for (int k = 0; k < 128; ++k) o = fmaf(sh[k], hW2[(size_t)k * 100 + t], o);
        out[(size_t)g * 100 + t] = o;
    }
}

// ---------------------------------------------------------------- launch
extern "C" void kernel_launch(void* const* d_in, const int* in_sizes, int n_in,
                              void* d_out, int out_size, void* d_ws, size_t ws_size,
                              hipStream_t stream) {
    const float* x     = (const float*)d_in[0];
    const int*   ei    = (const int*)d_in[1];
    const int*   batch = (const int*)d_in[2];
    const float* ea    = (const float*)d_in[3];
    const float* eeW1  = (const float*)d_in[4];
    const float* eeb1  = (const float*)d_in[5];
    const float* eeW2  = (const float*)d_in[6];
    const float* eeb2  = (const float*)d_in[7];
    const float* W[4]  = {(const float*)d_in[8], (const float*)d_in[10], (const float*)d_in[12], (const float*)d_in[14]};
    const float* cb[4] = {(const float*)d_in[9], (const float*)d_in[11], (const float*)d_in[13], (const float*)d_in[15]};
    const float* gm[4] = {(const float*)d_in[16], (const float*)d_in[18], (const float*)d_in[20], (const float*)d_in[22]};
    const float* be[4] = {(const float*)d_in[17], (const float*)d_in[19], (const float*)d_in[21], (const float*)d_in[23]};
    const float* resW  = (const float*)d_in[24];
    const float* resb  = (const float*)d_in[25];
    const float* hW1   = (const float*)d_in[26];
    const float* hb1   = (const float*)d_in[27];
    const float* hW2   = (const float*)d_in[28];
    const float* hb2   = (const float*)d_in[29];
    float* out = (float*)d_out;

    // workspace layout (~150 MB total)
    char* w = (char*)d_ws;
    auto alloc = [&](size_t bytes) { void* p = w; w += (bytes + 255) & ~(size_t)255; return p; };
    float*  ew     = (float*) alloc((size_t)EE * 4);          //  6.4 MB
    float*  dis    = (float*) alloc((size_t)NN * 4);          //  0.4 MB (deg then rsqrt in place)
    int*    cnt    = (int*)   alloc((size_t)NN * 4);          //  0.4 MB (reused as cursor)
    int*    rowptr = (int*)   alloc((size_t)(NN + 1) * 4);    //  0.4 MB
    int*    bsum   = (int*)   alloc(2048);
    int*    esrc   = (int*)   alloc((size_t)EE * 4);          //  6.4 MB
    float*  enorm  = (float*) alloc((size_t)EE * 4);          //  6.4 MB
    __bf16* xb     = (__bf16*)alloc((size_t)NN * INC * 2);    // 19.2 MB
    __bf16* hw     = (__bf16*)alloc((size_t)NN * HH * 2);     // 25.6 MB
    __bf16* bufA   = (__bf16*)alloc((size_t)NN * HH * 2);     // 25.6 MB
    __bf16* bufB   = (__bf16*)alloc((size_t)NN * HH * 2);     // 25.6 MB
    float*  xsum   = (float*) alloc((size_t)NN * HH * 4);     // 51.2 MB
    float*  gbuf   = (float*) alloc((size_t)GB * 256 * 4);    //  0.5 MB
    int*    cursor = cnt;   // cnt dead after scan1

    int nblkN = (NN + 255) / 256;            // 391
    int nblkE = (EE + 255) / 256;            // 6250
    int nblkEdgeMlp = (EE + 2047) / 2048;    // 782
    int nblkGemm = (NN + 63) / 64;           // 1563
    int nblkCast = (NN * INC / 4 + 255) / 256;

    k_init<<<nblkN, 256, 0, stream>>>(dis, cnt, NN);
    k_cast<<<nblkCast, 256, 0, stream>>>(x, xb, NN * INC / 4);
    k_edge_mlp<<<nblkEdgeMlp, 256, 0, stream>>>(ea, ei, eeW1, eeb1, eeW2, eeb2, ew, dis, cnt, EE);
    k_scan1<<<nblkN, 256, 0, stream>>>(cnt, rowptr, bsum, NN);
    k_scan2<<<1, 512, 0, stream>>>(bsum, nblkN);
    k_scan3<<<nblkN, 256, 0, stream>>>(rowptr, bsum, cursor, NN, EE);
    k_rsqrt<<<nblkN, 256, 0, stream>>>(dis, NN);
    k_fill<<<nblkE, 256, 0, stream>>>(ei, ew, dis, cursor, esrc, enorm, EE);

    // layer 0 (K=96): hw = x@W0; residual projection x@res_W+res_b into bufB (idle until L1 output)
    k_gemm_bf16<<<nblkGemm, 256, 0, stream>>>(xb, W[0], nullptr, hw, NN, INC);
    k_gemm_bf16<<<nblkGemm, 256, 0, stream>>>(xb, resW, resb, bufB, NN, INC);
    k_agg_ln<<<(NN + 3) / 4, 256, 0, stream>>>(hw, dis, rowptr, esrc, enorm,
                                               cb[0], gm[0], be[0], bufB, bufA, xsum, 1, NN);
    // layer 1
    k_gemm_bf16<<<nblkGemm, 256, 0, stream>>>(bufA, W[1], nullptr, hw, NN, HH);
    k_agg_ln<<<(NN + 3) / 4, 256, 0, stream>>>(hw, dis, rowptr, esrc, enorm,
                                               cb[1], gm[1], be[1], bufA, bufB, xsum, 0, NN);
    // layer 2
    k_gemm_bf16<<<nblkGemm, 256, 0, stream>>>(bufB, W[2], nullptr, hw, NN, HH);
    k_agg_ln<<<(NN + 3) / 4, 256, 0, stream>>>(hw, dis, rowptr, esrc, enorm,
                                               cb[2], gm[2], be[2], bufB, bufA, xsum, 0, NN);
    // layer 3
    k_gemm_bf16<<<nblkGemm, 256, 0, stream>>>(bufA, W[3], nullptr, hw, NN, HH);
    k_agg_ln<<<(NN + 3) / 4, 256, 0, stream>>>(hw, dis, rowptr, esrc, enorm,
                                               cb[3], gm[3], be[3], bufA, bufB, xsum, 0, NN);

    k_pool<<<GB, 128, 0, stream>>>(xsum, batch, gbuf, NN);
    k_head<<<GB, 128, 0, stream>>>(gbuf, hW1, hb1, hW2, hb2, out);
}

// Round 4
// 1331.928 us; speedup vs baseline: 1.1043x; 1.0499x over previous
//
#include <hip/hip_runtime.h>
#include <math.h>

#define NN 100000
#define EE 1600000
#define GB 512
#define INC 96
#define HH 128
#define CC 100

typedef __bf16 bf16x8 __attribute__((ext_vector_type(8)));
typedef __bf16 bf16x2 __attribute__((ext_vector_type(2)));
typedef float f32x4 __attribute__((ext_vector_type(4)));

// ---------------------------------------------------------------- init
__global__ __launch_bounds__(256) void k_init(float* __restrict__ deg, int* __restrict__ cnt, int n) {
    int i = blockIdx.x * 256 + threadIdx.x;
    if (i < n) { deg[i] = 1.0f; cnt[i] = 0; }   // self-loop weight 1 pre-seeded into degree
}

// ---------------------------------------------------------------- cast x (N*INC fp32) -> bf16
__global__ __launch_bounds__(256) void k_cast(const float* __restrict__ src, __bf16* __restrict__ dst, int n4) {
    int i = blockIdx.x * 256 + threadIdx.x;
    if (i >= n4) return;
    float4 v = *(const float4*)&src[(size_t)i * 4];
    bf16x2 a, b;
    a.x = (__bf16)v.x; a.y = (__bf16)v.y;
    b.x = (__bf16)v.z; b.y = (__bf16)v.w;
    *(bf16x2*)&dst[(size_t)i * 4]     = a;
    *(bf16x2*)&dst[(size_t)i * 4 + 2] = b;
}

// ---------------------------------------------------------------- transpose+cast weight W[K,128] f32 -> Wt[128,K] bf16
__global__ __launch_bounds__(256) void k_castT(const float* __restrict__ W, __bf16* __restrict__ Wt, int K) {
    int idx = blockIdx.x * 256 + threadIdx.x;
    if (idx >= K * 128) return;
    int k = idx >> 7, n = idx & 127;
    Wt[(size_t)n * K + k] = (__bf16)W[idx];
}

// ---------------------------------------------------------------- edge MLP: ew = softplus(relu(ea@W1+b1)@W2+b2)+1e-4
// 4 edges/thread (32 VGPRs of attrs -> no spill)
__global__ __launch_bounds__(256, 2) void k_edge_mlp(
    const float* __restrict__ ea, const int* __restrict__ ei,
    const float* __restrict__ W1, const float* __restrict__ b1,
    const float* __restrict__ W2, const float* __restrict__ b2,
    float* __restrict__ ew, float* __restrict__ deg, int* __restrict__ cnt, int E)
{
    __shared__ __align__(16) float sW1t[1024];   // [j][k] = W1[k*128+j]
    __shared__ __align__(16) float2 sB[128];     // (b1[j], W2[j])
    int t = threadIdx.x;
    for (int lin = t; lin < 1024; lin += 256)
        sW1t[lin] = W1[(lin & 7) * 128 + (lin >> 3)];
    if (t < 128) sB[t] = make_float2(b1[t], W2[t]);
    __syncthreads();

    int base = blockIdx.x * 1024;
    float4 a0[4], a1[4];
    float acc[4];
    int   ec[4];
    bool  vv[4];
#pragma unroll
    for (int ii = 0; ii < 4; ++ii) {
        int e = base + t + ii * 256;
        vv[ii] = (e < E);
        int e2 = vv[ii] ? e : 0;
        ec[ii] = e2;
        a0[ii] = *(const float4*)&ea[(size_t)e2 * 8];
        a1[ii] = *(const float4*)&ea[(size_t)e2 * 8 + 4];
        acc[ii] = 0.0f;
    }
    for (int j = 0; j < 128; ++j) {
        float4 w0 = *(const float4*)&sW1t[j * 8];
        float4 w1 = *(const float4*)&sW1t[j * 8 + 4];
        float2 bw = sB[j];
#pragma unroll
        for (int ii = 0; ii < 4; ++ii) {
            float h = bw.x;
            h = fmaf(a0[ii].x, w0.x, h); h = fmaf(a0[ii].y, w0.y, h);
            h = fmaf(a0[ii].z, w0.z, h); h = fmaf(a0[ii].w, w0.w, h);
            h = fmaf(a1[ii].x, w1.x, h); h = fmaf(a1[ii].y, w1.y, h);
            h = fmaf(a1[ii].z, w1.z, h); h = fmaf(a1[ii].w, w1.w, h);
            h = fmaxf(h, 0.0f);
            acc[ii] = fmaf(h, bw.y, acc[ii]);
        }
    }
    float b2v = b2[0];
#pragma unroll
    for (int ii = 0; ii < 4; ++ii) {
        if (!vv[ii]) continue;
        float x = acc[ii] + b2v;
        float sp = (x > 20.0f) ? x : log1pf(expf(x));
        float w = sp + 1e-4f;
        ew[ec[ii]] = w;
        int c = ei[E + ec[ii]];          // col = edge_index[1][e]
        atomicAdd(&deg[c], w);
        atomicAdd(&cnt[c], 1);
    }
}

// ---------------------------------------------------------------- prefix scan (3-kernel) over cnt -> rowptr
__global__ __launch_bounds__(256) void k_scan1(const int* __restrict__ cnt, int* __restrict__ rp,
                                               int* __restrict__ bsum, int n) {
    __shared__ int s[256];
    int t = threadIdx.x, i = blockIdx.x * 256 + t;
    int v = (i < n) ? cnt[i] : 0;
    s[t] = v; __syncthreads();
    for (int o = 1; o < 256; o <<= 1) {
        int x = (t >= o) ? s[t - o] : 0;
        __syncthreads();
        s[t] += x;
        __syncthreads();
    }
    if (i < n) rp[i] = s[t] - v;          // exclusive within block
    if (t == 255) bsum[blockIdx.x] = s[255];
}

__global__ __launch_bounds__(512) void k_scan2(int* __restrict__ bsum, int nb) {
    __shared__ int s[512];
    int t = threadIdx.x;
    int v = (t < nb) ? bsum[t] : 0;
    s[t] = v; __syncthreads();
    for (int o = 1; o < 512; o <<= 1) {
        int x = (t >= o) ? s[t - o] : 0;
        __syncthreads();
        s[t] += x;
        __syncthreads();
    }
    if (t < nb) bsum[t] = s[t] - v;       // exclusive block offsets
}

__global__ __launch_bounds__(256) void k_scan3(int* __restrict__ rp, const int* __restrict__ bsum,
                                               int* __restrict__ cursor, int n, int total) {
    int i = blockIdx.x * 256 + threadIdx.x;
    if (i < n) {
        int r = rp[i] + bsum[blockIdx.x];
        rp[i] = r;
        cursor[i] = r;
    }
    if (i == 0) rp[n] = total;
}

// ---------------------------------------------------------------- dis = rsqrt(deg) in place
__global__ __launch_bounds__(256) void k_rsqrt(float* __restrict__ d, int n) {
    int i = blockIdx.x * 256 + threadIdx.x;
    if (i < n) d[i] = rsqrtf(d[i]);       // deg >= 1 always
}

// ---------------------------------------------------------------- scatter edges into CSR (by dst), precompute norm
__global__ __launch_bounds__(256) void k_fill(const int* __restrict__ ei, const float* __restrict__ ew,
                                              const float* __restrict__ dis, int* __restrict__ cursor,
                                              int* __restrict__ esrc, float* __restrict__ enorm, int E) {
    int e = blockIdx.x * 256 + threadIdx.x;
    if (e >= E) return;
    int r = ei[e], c = ei[E + e];
    float wn = dis[r] * ew[e] * dis[c];
    int p = atomicAdd(&cursor[c], 1);
    esrc[p] = r;
    enorm[p] = wn;
}

// ---------------------------------------------------------------- bf16 MFMA GEMM: C[M,128] = A[M,K]@Bt^T (+bias)
// Bt is pre-transposed bf16 [128,K]. 64x128 tile / 256-thread block, one barrier, uint4 staging only.
__global__ __launch_bounds__(256) void k_gemm_bf16(
    const __bf16* __restrict__ A, const __bf16* __restrict__ Bt,
    const float* __restrict__ bias, __bf16* __restrict__ C, int M, int K)
{
    __shared__ __align__(16) __bf16 sA[64 * 136];
    __shared__ __align__(16) __bf16 sBt[128 * 136];
    int lstr = K + 8;
    int tid = threadIdx.x;
    int m0 = blockIdx.x * 64;
    int CHK = K >> 3;                       // 16B chunks per row (12 or 16)
    // stage A tile (64 x K)
    for (int c = tid; c < 64 * CHK; c += 256) {
        int row = c / CHK, kk = (c - row * CHK) * 8;
        int rowg = m0 + row; if (rowg >= M) rowg = M - 1;
        *(uint4*)&sA[row * lstr + kk] = *(const uint4*)&A[(size_t)rowg * K + kk];
    }
    // stage Bt (128 x K)
    for (int c = tid; c < 128 * CHK; c += 256) {
        int n = c / CHK, kk = (c - n * CHK) * 8;
        *(uint4*)&sBt[n * lstr + kk] = *(const uint4*)&Bt[(size_t)n * K + kk];
    }
    __syncthreads();

    int wv = tid >> 6, lane = tid & 63;
    int ln15 = lane & 15, quad = lane >> 4;
    int n0 = wv * 32;
    f32x4 acc[4][2];
#pragma unroll
    for (int mt = 0; mt < 4; ++mt)
#pragma unroll
        for (int nt = 0; nt < 2; ++nt) acc[mt][nt] = (f32x4){0.f, 0.f, 0.f, 0.f};

    for (int kc = 0; kc < K; kc += 32) {
        bf16x8 af[4], bfr[2];
#pragma unroll
        for (int mt = 0; mt < 4; ++mt)
            af[mt] = *(const bf16x8*)&sA[(mt * 16 + ln15) * lstr + kc + quad * 8];
#pragma unroll
        for (int nt = 0; nt < 2; ++nt)
            bfr[nt] = *(const bf16x8*)&sBt[(n0 + nt * 16 + ln15) * lstr + kc + quad * 8];
#pragma unroll
        for (int mt = 0; mt < 4; ++mt)
#pragma unroll
            for (int nt = 0; nt < 2; ++nt)
                acc[mt][nt] = __builtin_amdgcn_mfma_f32_16x16x32_bf16(af[mt], bfr[nt], acc[mt][nt], 0, 0, 0);
    }
#pragma unroll
    for (int nt = 0; nt < 2; ++nt) {
        int col = n0 + nt * 16 + ln15;
        float bv = bias ? bias[col] : 0.0f;
#pragma unroll
        for (int mt = 0; mt < 4; ++mt) {
#pragma unroll
            for (int r = 0; r < 4; ++r) {
                int row = m0 + mt * 16 + quad * 4 + r;
                if (row < M) C[(size_t)row * 128 + col] = (__bf16)(acc[mt][nt][r] + bv);
            }
        }
    }
}

// ---------------------------------------------------------------- aggregate + bias + LN + residual + relu + xsum
// one wave per node; hw/res/out in bf16, math + xsum in fp32
__global__ __launch_bounds__(256) void k_agg_ln(
    const __bf16* __restrict__ hw, const float* __restrict__ dis,
    const int* __restrict__ rowptr, const int* __restrict__ esrc,
    const float* __restrict__ enorm,
    const float* __restrict__ cb, const float* __restrict__ gam,
    const float* __restrict__ bet, const __bf16* __restrict__ res,
    __bf16* __restrict__ out, float* __restrict__ xsum, int first, int n)
{
    int wv = threadIdx.x >> 6;
    int lane = threadIdx.x & 63;
    int i = blockIdx.x * 4 + wv;
    if (i >= n) return;
    float di = dis[i];
    float sn = di * di;                       // self-loop norm = 1/deg
    bf16x2 h2 = *(const bf16x2*)&hw[(size_t)i * HH + lane * 2];
    float2 acc = make_float2((float)h2.x * sn, (float)h2.y * sn);
    int p1 = rowptr[i + 1];
    for (int p = rowptr[i]; p < p1; ++p) {
        int s = esrc[p];
        float wn = enorm[p];
        bf16x2 v2 = *(const bf16x2*)&hw[(size_t)s * HH + lane * 2];
        acc.x = fmaf((float)v2.x, wn, acc.x);
        acc.y = fmaf((float)v2.y, wn, acc.y);
    }
    float2 cbv = *(const float2*)&cb[lane * 2];
    acc.x += cbv.x; acc.y += cbv.y;
    // LayerNorm over 128 via wave reduction
    float s1 = acc.x + acc.y;
    float s2 = acc.x * acc.x + acc.y * acc.y;
#pragma unroll
    for (int o = 32; o > 0; o >>= 1) {
        s1 += __shfl_xor(s1, o, 64);
        s2 += __shfl_xor(s2, o, 64);
    }
    float mean = s1 * (1.0f / HH);
    float var = fmaxf(s2 * (1.0f / HH) - mean * mean, 0.0f);
    float rstd = rsqrtf(var + 1e-5f);
    float2 gv = *(const float2*)&gam[lane * 2];
    float2 bv = *(const float2*)&bet[lane * 2];
    bf16x2 r2 = *(const bf16x2*)&res[(size_t)i * HH + lane * 2];
    float hx = fmaxf(fmaf(gv.x, (acc.x - mean) * rstd, bv.x) + (float)r2.x, 0.0f);
    float hy = fmaxf(fmaf(gv.y, (acc.y - mean) * rstd, bv.y) + (float)r2.y, 0.0f);
    bf16x2 o2; o2.x = (__bf16)hx; o2.y = (__bf16)hy;
    *(bf16x2*)&out[(size_t)i * HH + lane * 2] = o2;
    float2 xs;
    if (first) {
        xs = make_float2(hx, hy);
    } else {
        xs = *(const float2*)&xsum[(size_t)i * HH + lane * 2];
        xs.x += hx; xs.y += hy;
    }
    *(float2*)&xsum[(size_t)i * HH + lane * 2] = xs;
}

// ---------------------------------------------------------------- mean/max pool per graph (batch sorted)
__global__ __launch_bounds__(128) void k_pool(const float* __restrict__ xsum, const int* __restrict__ batch,
                                              float* __restrict__ gbuf, int n) {
    int g = blockIdx.x, t = threadIdx.x;
    int lo = 0, hi = n;
    while (lo < hi) { int m = (lo + hi) >> 1; if (batch[m] < g) lo = m + 1; else hi = m; }
    int start = lo;
    lo = start; hi = n;
    while (lo < hi) { int m = (lo + hi) >> 1; if (batch[m] < g + 1) lo = m + 1; else hi = m; }
    int end = lo;
    float sum = 0.0f, mx = -INFINITY;
    for (int nd = start; nd < end; ++nd) {
        float v = xsum[(size_t)nd * HH + t] * 0.25f;
        sum += v;
        mx = fmaxf(mx, v);
    }
    int cntg = end - start;
    float mean = sum / fmaxf((float)cntg, 1.0f);
    gbuf[(size_t)g * 256 + t] = mean;
    gbuf[(size_t)g * 256 + 128 + t] = (cntg > 0) ? mx : 0.0f;
}

// ---------------------------------------------------------------- head: relu(g@hW1+hb1)@hW2+hb2
__global__ __launch_bounds__(128) void k_head(const float* __restrict__ gbuf,
                                              const float* __restrict__ hW1, const float* __restrict__ hb1,
                                              const float* __restrict__ hW2, const float* __restrict__ hb2,
                                              float* __restrict__ out) {
    __shared__ __align__(16) float sg[256];
    __shared__ __align__(16) float sh[128];
    int g = blockIdx.x, t = threadIdx.x;
    sg[t] = gbuf[(size_t)g * 256 + t];
    sg[t + 128] = gbuf[(size_t)g * 256 + 128 + t];
    __syncthreads();
    float h = hb1[t];
    for (int k = 0; k < 256; ++k) h = fmaf(sg[k], hW1[(size_t)k * 128 + t], h);
    sh[t] = fmaxf(h, 0.0f);
    __syncthreads();
    if (t < 100) {
        float o = hb2[t];
        for (int k = 0; k < 128; ++k) o = fmaf(sh[k], hW2[(size_t)k * 100 + t], o);
        out[(size_t)g * 100 + t] = o;
    }
}

// ---------------------------------------------------------------- launch
extern "C" void kernel_launch(void* const* d_in, const int* in_sizes, int n_in,
                              void* d_out, int out_size, void* d_ws, size_t ws_size,
                              hipStream_t stream) {
    const float* x     = (const float*)d_in[0];
    const int*   ei    = (const int*)d_in[1];
    const int*   batch = (const int*)d_in[2];
    const float* ea    = (const float*)d_in[3];
    const float* eeW1  = (const float*)d_in[4];
    const float* eeb1  = (const float*)d_in[5];
    const float* eeW2  = (const float*)d_in[6];
    const float* eeb2  = (const float*)d_in[7];
    const float* W[4]  = {(const float*)d_in[8], (const float*)d_in[10], (const float*)d_in[12], (const float*)d_in[14]};
    const float* cb[4] = {(const float*)d_in[9], (const float*)d_in[11], (const float*)d_in[13], (const float*)d_in[15]};
    const float* gm[4] = {(const float*)d_in[16], (const float*)d_in[18], (const float*)d_in[20], (const float*)d_in[22]};
    const float* be[4] = {(const float*)d_in[17], (const float*)d_in[19], (const float*)d_in[21], (const float*)d_in[23]};
    const float* resW  = (const float*)d_in[24];
    const float* resb  = (const float*)d_in[25];
    const float* hW1   = (const float*)d_in[26];
    const float* hb1   = (const float*)d_in[27];
    const float* hW2   = (const float*)d_in[28];
    const float* hb2   = (const float*)d_in[29];
    float* out = (float*)d_out;

    // workspace layout (~150 MB total)
    char* w = (char*)d_ws;
    auto alloc = [&](size_t bytes) { void* p = w; w += (bytes + 255) & ~(size_t)255; return p; };
    float*  ew     = (float*) alloc((size_t)EE * 4);          //  6.4 MB
    float*  dis    = (float*) alloc((size_t)NN * 4);          //  0.4 MB (deg then rsqrt in place)
    int*    cnt    = (int*)   alloc((size_t)NN * 4);          //  0.4 MB (reused as cursor)
    int*    rowptr = (int*)   alloc((size_t)(NN + 1) * 4);    //  0.4 MB
    int*    bsum   = (int*)   alloc(2048);
    int*    esrc   = (int*)   alloc((size_t)EE * 4);          //  6.4 MB
    float*  enorm  = (float*) alloc((size_t)EE * 4);          //  6.4 MB
    __bf16* xb     = (__bf16*)alloc((size_t)NN * INC * 2);    // 19.2 MB
    __bf16* hw     = (__bf16*)alloc((size_t)NN * HH * 2);     // 25.6 MB
    __bf16* bufA   = (__bf16*)alloc((size_t)NN * HH * 2);     // 25.6 MB
    __bf16* bufB   = (__bf16*)alloc((size_t)NN * HH * 2);     // 25.6 MB
    float*  xsum   = (float*) alloc((size_t)NN * HH * 4);     // 51.2 MB
    float*  gbuf   = (float*) alloc((size_t)GB * 256 * 4);    //  0.5 MB
    __bf16* wt0    = (__bf16*)alloc((size_t)INC * HH * 2);    // pre-transposed bf16 weights
    __bf16* wtR    = (__bf16*)alloc((size_t)INC * HH * 2);
    __bf16* wt1    = (__bf16*)alloc((size_t)HH * HH * 2);
    __bf16* wt2    = (__bf16*)alloc((size_t)HH * HH * 2);
    __bf16* wt3    = (__bf16*)alloc((size_t)HH * HH * 2);
    int*    cursor = cnt;   // cnt dead after scan1

    int nblkN = (NN + 255) / 256;            // 391
    int nblkE = (EE + 255) / 256;            // 6250
    int nblkEdgeMlp = (EE + 1023) / 1024;    // 1563
    int nblkGemm = (NN + 63) / 64;           // 1563
    int nblkCast = (NN * INC / 4 + 255) / 256;
    int nblkT96 = (INC * 128 + 255) / 256;   // 48
    int nblkT128 = (HH * 128 + 255) / 256;   // 64

    k_init<<<nblkN, 256, 0, stream>>>(dis, cnt, NN);
    k_cast<<<nblkCast, 256, 0, stream>>>(x, xb, NN * INC / 4);
    k_castT<<<nblkT96, 256, 0, stream>>>(W[0], wt0, INC);
    k_castT<<<nblkT96, 256, 0, stream>>>(resW, wtR, INC);
    k_castT<<<nblkT128, 256, 0, stream>>>(W[1], wt1, HH);
    k_castT<<<nblkT128, 256, 0, stream>>>(W[2], wt2, HH);
    k_castT<<<nblkT128, 256, 0, stream>>>(W[3], wt3, HH);
    k_edge_mlp<<<nblkEdgeMlp, 256, 0, stream>>>(ea, ei, eeW1, eeb1, eeW2, eeb2, ew, dis, cnt, EE);
    k_scan1<<<nblkN, 256, 0, stream>>>(cnt, rowptr, bsum, NN);
    k_scan2<<<1, 512, 0, stream>>>(bsum, nblkN);
    k_scan3<<<nblkN, 256, 0, stream>>>(rowptr, bsum, cursor, NN, EE);
    k_rsqrt<<<nblkN, 256, 0, stream>>>(dis, NN);
    k_fill<<<nblkE, 256, 0, stream>>>(ei, ew, dis, cursor, esrc, enorm, EE);

    // layer 0 (K=96): hw = x@W0; residual projection x@res_W+res_b into bufB (idle until L1 output)
    k_gemm_bf16<<<nblkGemm, 256, 0, stream>>>(xb, wt0, nullptr, hw, NN, INC);
    k_gemm_bf16<<<nblkGemm, 256, 0, stream>>>(xb, wtR, resb, bufB, NN, INC);
    k_agg_ln<<<(NN + 3) / 4, 256, 0, stream>>>(hw, dis, rowptr, esrc, enorm,
                                               cb[0], gm[0], be[0], bufB, bufA, xsum, 1, NN);
    // layer 1
    k_gemm_bf16<<<nblkGemm, 256, 0, stream>>>(bufA, wt1, nullptr, hw, NN, HH);
    k_agg_ln<<<(NN + 3) / 4, 256, 0, stream>>>(hw, dis, rowptr, esrc, enorm,
                                               cb[1], gm[1], be[1], bufA, bufB, xsum, 0, NN);
    // layer 2
    k_gemm_bf16<<<nblkGemm, 256, 0, stream>>>(bufB, wt2, nullptr, hw, NN, HH);
    k_agg_ln<<<(NN + 3) / 4, 256, 0, stream>>>(hw, dis, rowptr, esrc, enorm,
                                               cb[2], gm[2], be[2], bufB, bufA, xsum, 0, NN);
    // layer 3
    k_gemm_bf16<<<nblkGemm, 256, 0, stream>>>(bufA, wt3, nullptr, hw, NN, HH);
    k_agg_ln<<<(NN + 3) / 4, 256, 0, stream>>>(hw, dis, rowptr, esrc, enorm,
                                               cb[3], gm[3], be[3], bufA, bufB, xsum, 0, NN);

    k_pool<<<GB, 128, 0, stream>>>(xsum, batch, gbuf, NN);
    k_head<<<GB, 128, 0, stream>>>(gbuf, hW1, hb1, hW2, hb2, out);
}

// Round 5
// 1006.884 us; speedup vs baseline: 1.4608x; 1.3228x over previous
//
#include <hip/hip_runtime.h>
#include <math.h>

#define NN 100000
#define EE 1600000
#define GB 512
#define INC 96
#define HH 128
#define CC 100

typedef __bf16 bf16x8 __attribute__((ext_vector_type(8)));
typedef __bf16 bf16x2 __attribute__((ext_vector_type(2)));
typedef float f32x4 __attribute__((ext_vector_type(4)));

// ---------------------------------------------------------------- init
__global__ __launch_bounds__(256) void k_init(float* __restrict__ deg, int* __restrict__ cnt, int n) {
    int i = blockIdx.x * 256 + threadIdx.x;
    if (i < n) { deg[i] = 1.0f; cnt[i] = 0; }   // self-loop weight 1 pre-seeded into degree
}

// ---------------------------------------------------------------- cast x (N*INC fp32) -> bf16
__global__ __launch_bounds__(256) void k_cast(const float* __restrict__ src, __bf16* __restrict__ dst, int n4) {
    int i = blockIdx.x * 256 + threadIdx.x;
    if (i >= n4) return;
    float4 v = *(const float4*)&src[(size_t)i * 4];
    bf16x2 a, b;
    a.x = (__bf16)v.x; a.y = (__bf16)v.y;
    b.x = (__bf16)v.z; b.y = (__bf16)v.w;
    *(bf16x2*)&dst[(size_t)i * 4]     = a;
    *(bf16x2*)&dst[(size_t)i * 4 + 2] = b;
}

// ---------------------------------------------------------------- transpose+cast weight W[K,128] f32 -> Wt[128,K] bf16
__global__ __launch_bounds__(256) void k_castT(const float* __restrict__ W, __bf16* __restrict__ Wt, int K) {
    int idx = blockIdx.x * 256 + threadIdx.x;
    if (idx >= K * 128) return;
    int k = idx >> 7, n = idx & 127;
    Wt[(size_t)n * K + k] = (__bf16)W[idx];
}

// ---------------------------------------------------------------- edge MLP: ew = softplus(relu(ea@W1+b1)@W2+b2)+1e-4
__global__ __launch_bounds__(256, 2) void k_edge_mlp(
    const float* __restrict__ ea, const int* __restrict__ ei,
    const float* __restrict__ W1, const float* __restrict__ b1,
    const float* __restrict__ W2, const float* __restrict__ b2,
    float* __restrict__ ew, float* __restrict__ deg, int* __restrict__ cnt, int E)
{
    __shared__ __align__(16) float sW1t[1024];   // [j][k] = W1[k*128+j]
    __shared__ __align__(16) float2 sB[128];     // (b1[j], W2[j])
    int t = threadIdx.x;
    for (int lin = t; lin < 1024; lin += 256)
        sW1t[lin] = W1[(lin & 7) * 128 + (lin >> 3)];
    if (t < 128) sB[t] = make_float2(b1[t], W2[t]);
    __syncthreads();

    int base = blockIdx.x * 1024;
    float4 a0[4], a1[4];
    float acc[4];
    int   ec[4];
    bool  vv[4];
#pragma unroll
    for (int ii = 0; ii < 4; ++ii) {
        int e = base + t + ii * 256;
        vv[ii] = (e < E);
        int e2 = vv[ii] ? e : 0;
        ec[ii] = e2;
        a0[ii] = *(const float4*)&ea[(size_t)e2 * 8];
        a1[ii] = *(const float4*)&ea[(size_t)e2 * 8 + 4];
        acc[ii] = 0.0f;
    }
    for (int j = 0; j < 128; ++j) {
        float4 w0 = *(const float4*)&sW1t[j * 8];
        float4 w1 = *(const float4*)&sW1t[j * 8 + 4];
        float2 bw = sB[j];
#pragma unroll
        for (int ii = 0; ii < 4; ++ii) {
            float h = bw.x;
            h = fmaf(a0[ii].x, w0.x, h); h = fmaf(a0[ii].y, w0.y, h);
            h = fmaf(a0[ii].z, w0.z, h); h = fmaf(a0[ii].w, w0.w, h);
            h = fmaf(a1[ii].x, w1.x, h); h = fmaf(a1[ii].y, w1.y, h);
            h = fmaf(a1[ii].z, w1.z, h); h = fmaf(a1[ii].w, w1.w, h);
            h = fmaxf(h, 0.0f);
            acc[ii] = fmaf(h, bw.y, acc[ii]);
        }
    }
    float b2v = b2[0];
#pragma unroll
    for (int ii = 0; ii < 4; ++ii) {
        if (!vv[ii]) continue;
        float x = acc[ii] + b2v;
        float sp = (x > 20.0f) ? x : log1pf(expf(x));
        float w = sp + 1e-4f;
        ew[ec[ii]] = w;
        int c = ei[E + ec[ii]];          // col = edge_index[1][e]
        atomicAdd(&deg[c], w);
        atomicAdd(&cnt[c], 1);
    }
}

// ---------------------------------------------------------------- prefix scan (3-kernel) over cnt -> rowptr
__global__ __launch_bounds__(256) void k_scan1(const int* __restrict__ cnt, int* __restrict__ rp,
                                               int* __restrict__ bsum, int n) {
    __shared__ int s[256];
    int t = threadIdx.x, i = blockIdx.x * 256 + t;
    int v = (i < n) ? cnt[i] : 0;
    s[t] = v; __syncthreads();
    for (int o = 1; o < 256; o <<= 1) {
        int x = (t >= o) ? s[t - o] : 0;
        __syncthreads();
        s[t] += x;
        __syncthreads();
    }
    if (i < n) rp[i] = s[t] - v;          // exclusive within block
    if (t == 255) bsum[blockIdx.x] = s[255];
}

__global__ __launch_bounds__(512) void k_scan2(int* __restrict__ bsum, int nb) {
    __shared__ int s[512];
    int t = threadIdx.x;
    int v = (t < nb) ? bsum[t] : 0;
    s[t] = v; __syncthreads();
    for (int o = 1; o < 512; o <<= 1) {
        int x = (t >= o) ? s[t - o] : 0;
        __syncthreads();
        s[t] += x;
        __syncthreads();
    }
    if (t < nb) bsum[t] = s[t] - v;       // exclusive block offsets
}

__global__ __launch_bounds__(256) void k_scan3(int* __restrict__ rp, const int* __restrict__ bsum,
                                               int* __restrict__ cursor, int n, int total) {
    int i = blockIdx.x * 256 + threadIdx.x;
    if (i < n) {
        int r = rp[i] + bsum[blockIdx.x];
        rp[i] = r;
        cursor[i] = r;
    }
    if (i == 0) rp[n] = total;
}

// ---------------------------------------------------------------- dis = rsqrt(deg) in place
__global__ __launch_bounds__(256) void k_rsqrt(float* __restrict__ d, int n) {
    int i = blockIdx.x * 256 + threadIdx.x;
    if (i < n) d[i] = rsqrtf(d[i]);       // deg >= 1 always
}

// ---------------------------------------------------------------- scatter edges into CSR (by dst), precompute norm
__global__ __launch_bounds__(256) void k_fill(const int* __restrict__ ei, const float* __restrict__ ew,
                                              const float* __restrict__ dis, int* __restrict__ cursor,
                                              int* __restrict__ esrc, float* __restrict__ enorm, int E) {
    int e = blockIdx.x * 256 + threadIdx.x;
    if (e >= E) return;
    int r = ei[e], c = ei[E + e];
    float wn = dis[r] * ew[e] * dis[c];
    int p = atomicAdd(&cursor[c], 1);
    esrc[p] = r;
    enorm[p] = wn;
}

// ---------------------------------------------------------------- bf16 MFMA GEMM, LDS-free: C[M,128] = A[M,K]@Bt^T (+bias)
// A row-major bf16 [M,K]; Bt pre-transposed bf16 [128,K]. Fragment loads are direct
// 16B global loads (A frag = 8 contiguous k-elems at row m, offset quad*8). No LDS, no barriers.
__global__ __launch_bounds__(256) void k_gemm_bf16(
    const __bf16* __restrict__ A, const __bf16* __restrict__ Bt,
    const float* __restrict__ bias, __bf16* __restrict__ C, int M, int K)
{
    int tid = threadIdx.x;
    int wv = tid >> 6, lane = tid & 63;
    int ln15 = lane & 15, quad = lane >> 4;
    int m0 = blockIdx.x * 64;
    int n0 = wv * 32;
    f32x4 acc[4][2];
#pragma unroll
    for (int mt = 0; mt < 4; ++mt)
#pragma unroll
        for (int nt = 0; nt < 2; ++nt) acc[mt][nt] = (f32x4){0.f, 0.f, 0.f, 0.f};

    // row indices (clamped for the M tail; stores are guarded)
    int rowm[4];
#pragma unroll
    for (int mt = 0; mt < 4; ++mt) {
        int r = m0 + mt * 16 + ln15;
        rowm[mt] = r < M ? r : M - 1;
    }
    for (int kc = 0; kc < K; kc += 32) {
        bf16x8 af[4], bfr[2];
#pragma unroll
        for (int mt = 0; mt < 4; ++mt)
            af[mt] = *(const bf16x8*)&A[(size_t)rowm[mt] * K + kc + quad * 8];
#pragma unroll
        for (int nt = 0; nt < 2; ++nt)
            bfr[nt] = *(const bf16x8*)&Bt[(size_t)(n0 + nt * 16 + ln15) * K + kc + quad * 8];
#pragma unroll
        for (int mt = 0; mt < 4; ++mt)
#pragma unroll
            for (int nt = 0; nt < 2; ++nt)
                acc[mt][nt] = __builtin_amdgcn_mfma_f32_16x16x32_bf16(af[mt], bfr[nt], acc[mt][nt], 0, 0, 0);
    }
#pragma unroll
    for (int nt = 0; nt < 2; ++nt) {
        int col = n0 + nt * 16 + ln15;
        float bv = bias ? bias[col] : 0.0f;
#pragma unroll
        for (int mt = 0; mt < 4; ++mt) {
#pragma unroll
            for (int r = 0; r < 4; ++r) {
                int row = m0 + mt * 16 + quad * 4 + r;
                if (row < M) C[(size_t)row * 128 + col] = (__bf16)(acc[mt][nt][r] + bv);
            }
        }
    }
}

// ---------------------------------------------------------------- aggregate + bias + LN + residual + relu
// one wave per node; unroll-8 edge loop for 8 outstanding gathers
__global__ __launch_bounds__(256) void k_agg_ln(
    const __bf16* __restrict__ hw, const float* __restrict__ dis,
    const int* __restrict__ rowptr, const int* __restrict__ esrc,
    const float* __restrict__ enorm,
    const float* __restrict__ cb, const float* __restrict__ gam,
    const float* __restrict__ bet, const __bf16* __restrict__ res,
    __bf16* __restrict__ out, int n)
{
    int wv = threadIdx.x >> 6;
    int lane = threadIdx.x & 63;
    int i = blockIdx.x * 4 + wv;
    if (i >= n) return;
    float di = dis[i];
    float sn = di * di;                       // self-loop norm = 1/deg
    bf16x2 h2 = *(const bf16x2*)&hw[(size_t)i * HH + lane * 2];
    float2 acc = make_float2((float)h2.x * sn, (float)h2.y * sn);
    int p = rowptr[i], p1 = rowptr[i + 1];
    for (; p + 8 <= p1; p += 8) {
        int s[8]; float wn[8]; bf16x2 v[8];
#pragma unroll
        for (int k = 0; k < 8; ++k) { s[k] = esrc[p + k]; wn[k] = enorm[p + k]; }
#pragma unroll
        for (int k = 0; k < 8; ++k) v[k] = *(const bf16x2*)&hw[(size_t)s[k] * HH + lane * 2];
#pragma unroll
        for (int k = 0; k < 8; ++k) {
            acc.x = fmaf((float)v[k].x, wn[k], acc.x);
            acc.y = fmaf((float)v[k].y, wn[k], acc.y);
        }
    }
    for (; p < p1; ++p) {
        int s = esrc[p];
        float wn = enorm[p];
        bf16x2 v2 = *(const bf16x2*)&hw[(size_t)s * HH + lane * 2];
        acc.x = fmaf((float)v2.x, wn, acc.x);
        acc.y = fmaf((float)v2.y, wn, acc.y);
    }
    float2 cbv = *(const float2*)&cb[lane * 2];
    acc.x += cbv.x; acc.y += cbv.y;
    // LayerNorm over 128 via wave reduction
    float s1 = acc.x + acc.y;
    float s2 = acc.x * acc.x + acc.y * acc.y;
#pragma unroll
    for (int o = 32; o > 0; o >>= 1) {
        s1 += __shfl_xor(s1, o, 64);
        s2 += __shfl_xor(s2, o, 64);
    }
    float mean = s1 * (1.0f / HH);
    float var = fmaxf(s2 * (1.0f / HH) - mean * mean, 0.0f);
    float rstd = rsqrtf(var + 1e-5f);
    float2 gv = *(const float2*)&gam[lane * 2];
    float2 bv = *(const float2*)&bet[lane * 2];
    bf16x2 r2 = *(const bf16x2*)&res[(size_t)i * HH + lane * 2];
    float hx = fmaxf(fmaf(gv.x, (acc.x - mean) * rstd, bv.x) + (float)r2.x, 0.0f);
    float hy = fmaxf(fmaf(gv.y, (acc.y - mean) * rstd, bv.y) + (float)r2.y, 0.0f);
    bf16x2 o2; o2.x = (__bf16)hx; o2.y = (__bf16)hy;
    *(bf16x2*)&out[(size_t)i * HH + lane * 2] = o2;
}

// ---------------------------------------------------------------- mean/max pool per graph over (l0+l1+l2+l3)/4
__global__ __launch_bounds__(128) void k_pool(
    const __bf16* __restrict__ l0, const __bf16* __restrict__ l1,
    const __bf16* __restrict__ l2, const __bf16* __restrict__ l3,
    const int* __restrict__ batch, float* __restrict__ gbuf, int n)
{
    int g = blockIdx.x, t = threadIdx.x;
    int lo = 0, hi = n;
    while (lo < hi) { int m = (lo + hi) >> 1; if (batch[m] < g) lo = m + 1; else hi = m; }
    int start = lo;
    lo = start; hi = n;
    while (lo < hi) { int m = (lo + hi) >> 1; if (batch[m] < g + 1) lo = m + 1; else hi = m; }
    int end = lo;
    float sum = 0.0f, mx = -INFINITY;
    for (int nd = start; nd < end; ++nd) {
        size_t off = (size_t)nd * HH + t;
        float v = ((float)l0[off] + (float)l1[off] + (float)l2[off] + (float)l3[off]) * 0.25f;
        sum += v;
        mx = fmaxf(mx, v);
    }
    int cntg = end - start;
    float mean = sum / fmaxf((float)cntg, 1.0f);
    gbuf[(size_t)g * 256 + t] = mean;
    gbuf[(size_t)g * 256 + 128 + t] = (cntg > 0) ? mx : 0.0f;
}

// ---------------------------------------------------------------- head: relu(g@hW1+hb1)@hW2+hb2
__global__ __launch_bounds__(128) void k_head(const float* __restrict__ gbuf,
                                              const float* __restrict__ hW1, const float* __restrict__ hb1,
                                              const float* __restrict__ hW2, const float* __restrict__ hb2,
                                              float* __restrict__ out) {
    __shared__ __align__(16) float sg[256];
    __shared__ __align__(16) float sh[128];
    int g = blockIdx.x, t = threadIdx.x;
    sg[t] = gbuf[(size_t)g * 256 + t];
    sg[t + 128] = gbuf[(size_t)g * 256 + 128 + t];
    __syncthreads();
    float h = hb1[t];
    for (int k = 0; k < 256; ++k) h = fmaf(sg[k], hW1[(size_t)k * 128 + t], h);
    sh[t] = fmaxf(h, 0.0f);
    __syncthreads();
    if (t < 100) {
        float o = hb2[t];
        for (int k = 0; k < 128; ++k) o = fmaf(sh[k], hW2[(size_t)k * 100 + t], o);
        out[(size_t)g * 100 + t] = o;
    }
}

// ---------------------------------------------------------------- launch
extern "C" void kernel_launch(void* const* d_in, const int* in_sizes, int n_in,
                              void* d_out, int out_size, void* d_ws, size_t ws_size,
                              hipStream_t stream) {
    const float* x     = (const float*)d_in[0];
    const int*   ei    = (const int*)d_in[1];
    const int*   batch = (const int*)d_in[2];
    const float* ea    = (const float*)d_in[3];
    const float* eeW1  = (const float*)d_in[4];
    const float* eeb1  = (const float*)d_in[5];
    const float* eeW2  = (const float*)d_in[6];
    const float* eeb2  = (const float*)d_in[7];
    const float* W[4]  = {(const float*)d_in[8], (const float*)d_in[10], (const float*)d_in[12], (const float*)d_in[14]};
    const float* cb[4] = {(const float*)d_in[9], (const float*)d_in[11], (const float*)d_in[13], (const float*)d_in[15]};
    const float* gm[4] = {(const float*)d_in[16], (const float*)d_in[18], (const float*)d_in[20], (const float*)d_in[22]};
    const float* be[4] = {(const float*)d_in[17], (const float*)d_in[19], (const float*)d_in[21], (const float*)d_in[23]};
    const float* resW  = (const float*)d_in[24];
    const float* resb  = (const float*)d_in[25];
    const float* hW1   = (const float*)d_in[26];
    const float* hb1   = (const float*)d_in[27];
    const float* hW2   = (const float*)d_in[28];
    const float* hb2   = (const float*)d_in[29];
    float* out = (float*)d_out;

    // workspace layout (~194 MB total)
    char* w = (char*)d_ws;
    auto alloc = [&](size_t bytes) { void* p = w; w += (bytes + 255) & ~(size_t)255; return p; };
    float*  ew     = (float*) alloc((size_t)EE * 4);          //  6.4 MB
    float*  dis    = (float*) alloc((size_t)NN * 4);          //  0.4 MB
    int*    cnt    = (int*)   alloc((size_t)NN * 4);          //  0.4 MB (reused as cursor)
    int*    rowptr = (int*)   alloc((size_t)(NN + 1) * 4);    //  0.4 MB
    int*    bsum   = (int*)   alloc(2048);
    int*    esrc   = (int*)   alloc((size_t)EE * 4);          //  6.4 MB
    float*  enorm  = (float*) alloc((size_t)EE * 4);          //  6.4 MB
    __bf16* xb     = (__bf16*)alloc((size_t)NN * INC * 2);    // 19.2 MB
    __bf16* hw     = (__bf16*)alloc((size_t)NN * HH * 2);     // 25.6 MB
    __bf16* res0   = (__bf16*)alloc((size_t)NN * HH * 2);     // 25.6 MB
    __bf16* lout[4];
    for (int i = 0; i < 4; ++i) lout[i] = (__bf16*)alloc((size_t)NN * HH * 2);  // 4 x 25.6 MB
    float*  gbuf   = (float*) alloc((size_t)GB * 256 * 4);    //  0.5 MB
    __bf16* wt0    = (__bf16*)alloc((size_t)INC * HH * 2);
    __bf16* wtR    = (__bf16*)alloc((size_t)INC * HH * 2);
    __bf16* wt1    = (__bf16*)alloc((size_t)HH * HH * 2);
    __bf16* wt2    = (__bf16*)alloc((size_t)HH * HH * 2);
    __bf16* wt3    = (__bf16*)alloc((size_t)HH * HH * 2);
    __bf16* wtc[4] = {wt0, wt1, wt2, wt3};
    int*    cursor = cnt;   // cnt dead after scan1

    int nblkN = (NN + 255) / 256;            // 391
    int nblkE = (EE + 255) / 256;            // 6250
    int nblkEdgeMlp = (EE + 1023) / 1024;    // 1563
    int nblkGemm = (NN + 63) / 64;           // 1563
    int nblkCast = (NN * INC / 4 + 255) / 256;
    int nblkT96 = (INC * 128 + 255) / 256;   // 48
    int nblkT128 = (HH * 128 + 255) / 256;   // 64

    k_init<<<nblkN, 256, 0, stream>>>(dis, cnt, NN);
    k_cast<<<nblkCast, 256, 0, stream>>>(x, xb, NN * INC / 4);
    k_castT<<<nblkT96, 256, 0, stream>>>(W[0], wt0, INC);
    k_castT<<<nblkT96, 256, 0, stream>>>(resW, wtR, INC);
    k_castT<<<nblkT128, 256, 0, stream>>>(W[1], wt1, HH);
    k_castT<<<nblkT128, 256, 0, stream>>>(W[2], wt2, HH);
    k_castT<<<nblkT128, 256, 0, stream>>>(W[3], wt3, HH);
    k_edge_mlp<<<nblkEdgeMlp, 256, 0, stream>>>(ea, ei, eeW1, eeb1, eeW2, eeb2, ew, dis, cnt, EE);
    k_scan1<<<nblkN, 256, 0, stream>>>(cnt, rowptr, bsum, NN);
    k_scan2<<<1, 512, 0, stream>>>(bsum, nblkN);
    k_scan3<<<nblkN, 256, 0, stream>>>(rowptr, bsum, cursor, NN, EE);
    k_rsqrt<<<nblkN, 256, 0, stream>>>(dis, NN);
    k_fill<<<nblkE, 256, 0, stream>>>(ei, ew, dis, cursor, esrc, enorm, EE);

    // layer 0 (K=96): hw = x@W0; res0 = x@res_W + res_b
    k_gemm_bf16<<<nblkGemm, 256, 0, stream>>>(xb, wt0, nullptr, hw, NN, INC);
    k_gemm_bf16<<<nblkGemm, 256, 0, stream>>>(xb, wtR, resb, res0, NN, INC);
    k_agg_ln<<<(NN + 3) / 4, 256, 0, stream>>>(hw, dis, rowptr, esrc, enorm,
                                               cb[0], gm[0], be[0], res0, lout[0], NN);
    // layers 1..3
    for (int l = 1; l < 4; ++l) {
        k_gemm_bf16<<<nblkGemm, 256, 0, stream>>>(lout[l - 1], wtc[l], nullptr, hw, NN, HH);
        k_agg_ln<<<(NN + 3) / 4, 256, 0, stream>>>(hw, dis, rowptr, esrc, enorm,
                                                   cb[l], gm[l], be[l], lout[l - 1], lout[l], NN);
    }

    k_pool<<<GB, 128, 0, stream>>>(lout[0], lout[1], lout[2], lout[3], batch, gbuf, NN);
    k_head<<<GB, 128, 0, stream>>>(gbuf, hW1, hb1, hW2, hb2, out);
}

// Round 6
// 973.875 us; speedup vs baseline: 1.5103x; 1.0339x over previous
//
#include <hip/hip_runtime.h>
#include <math.h>

#define NN 100000
#define EE 1600000
#define GB 512
#define INC 96
#define HH 128
#define CC 100

typedef __bf16 bf16x8 __attribute__((ext_vector_type(8)));
typedef __bf16 bf16x2 __attribute__((ext_vector_type(2)));
typedef float f32x4 __attribute__((ext_vector_type(4)));

// ---------------------------------------------------------------- init
__global__ __launch_bounds__(256) void k_init(float* __restrict__ deg, int* __restrict__ cnt, int n) {
    int i = blockIdx.x * 256 + threadIdx.x;
    if (i < n) { deg[i] = 1.0f; cnt[i] = 0; }   // self-loop weight 1 pre-seeded into degree
}

// ---------------------------------------------------------------- cast x (N*INC fp32) -> bf16
__global__ __launch_bounds__(256) void k_cast(const float* __restrict__ src, __bf16* __restrict__ dst, int n4) {
    int i = blockIdx.x * 256 + threadIdx.x;
    if (i >= n4) return;
    float4 v = *(const float4*)&src[(size_t)i * 4];
    bf16x2 a, b;
    a.x = (__bf16)v.x; a.y = (__bf16)v.y;
    b.x = (__bf16)v.z; b.y = (__bf16)v.w;
    *(bf16x2*)&dst[(size_t)i * 4]     = a;
    *(bf16x2*)&dst[(size_t)i * 4 + 2] = b;
}

// ---------------------------------------------------------------- transpose+cast weight W[K,128] f32 -> Wt[128,K] bf16
__global__ __launch_bounds__(256) void k_castT(const float* __restrict__ W, __bf16* __restrict__ Wt, int K) {
    int idx = blockIdx.x * 256 + threadIdx.x;
    if (idx >= K * 128) return;
    int k = idx >> 7, n = idx & 127;
    Wt[(size_t)n * K + k] = (__bf16)W[idx];
}

// ---------------------------------------------------------------- build W1 MFMA B-fragments (8 tiles x 64 lanes x 8 bf16)
// B-frag layout for mfma_16x16x32_bf16: lane holds B[k=quad*8+j][n=lane&15]; K padded 8->32 (quads 1-3 zero)
__global__ __launch_bounds__(512) void k_prep_w1(const float* __restrict__ W1, __bf16* __restrict__ w1f) {
    int tid = threadIdx.x;            // 512 = 8 tiles x 64 lanes
    int t = tid >> 6, lane = tid & 63;
    int ln15 = lane & 15, quad = lane >> 4;
    bf16x8 v = {};
    if (quad == 0) {
#pragma unroll
        for (int j = 0; j < 8; ++j) v[j] = (__bf16)W1[j * 128 + t * 16 + ln15];
    }
    *(bf16x8*)&w1f[(size_t)(t * 64 + lane) * 8] = v;
}

// ---------------------------------------------------------------- edge MLP via MFMA: ew = softplus(relu(ea@W1+b1)@W2+b2)+1e-4
// block = 4 waves x 32 edges = 128 edges. E = 1.6e6 divisible by 128 -> no tail.
__global__ __launch_bounds__(256) void k_edge_mlp_mfma(
    const float* __restrict__ ea, const int* __restrict__ ei,
    const __bf16* __restrict__ w1f, const float* __restrict__ b1,
    const float* __restrict__ W2, const float* __restrict__ b2,
    float* __restrict__ ew, float* __restrict__ deg, int* __restrict__ cnt, int E)
{
    __shared__ float sDot[128];
    int tid = threadIdx.x, wv = tid >> 6, lane = tid & 63;
    int ln15 = lane & 15, quad = lane >> 4;
    int ebase = blockIdx.x * 128 + wv * 32;

    // B fragments (pre-swizzled)
    bf16x8 bfr[8];
#pragma unroll
    for (int t = 0; t < 8; ++t) bfr[t] = *(const bf16x8*)&w1f[(size_t)(t * 64 + lane) * 8];

    // A fragments: 2 tiles of 16 edges; quad 0 holds k=0..7 (the 8 attrs), quads 1-3 zero
    bf16x8 a0 = {}, a1 = {};
    if (quad == 0) {
        const float* p0 = &ea[(size_t)(ebase + ln15) * 8];
        float4 u0 = *(const float4*)p0, u1 = *(const float4*)(p0 + 4);
        a0[0] = (__bf16)u0.x; a0[1] = (__bf16)u0.y; a0[2] = (__bf16)u0.z; a0[3] = (__bf16)u0.w;
        a0[4] = (__bf16)u1.x; a0[5] = (__bf16)u1.y; a0[6] = (__bf16)u1.z; a0[7] = (__bf16)u1.w;
        const float* p1 = &ea[(size_t)(ebase + 16 + ln15) * 8];
        float4 w0 = *(const float4*)p1, w1v = *(const float4*)(p1 + 4);
        a1[0] = (__bf16)w0.x; a1[1] = (__bf16)w0.y; a1[2] = (__bf16)w0.z; a1[3] = (__bf16)w0.w;
        a1[4] = (__bf16)w1v.x; a1[5] = (__bf16)w1v.y; a1[6] = (__bf16)w1v.z; a1[7] = (__bf16)w1v.w;
    }

    f32x4 d0 = {0.f, 0.f, 0.f, 0.f}, d1 = {0.f, 0.f, 0.f, 0.f};
#pragma unroll
    for (int t = 0; t < 8; ++t) {
        f32x4 z = {0.f, 0.f, 0.f, 0.f};
        f32x4 c0 = __builtin_amdgcn_mfma_f32_16x16x32_bf16(a0, bfr[t], z, 0, 0, 0);
        f32x4 c1 = __builtin_amdgcn_mfma_f32_16x16x32_bf16(a1, bfr[t], z, 0, 0, 0);
        int col = t * 16 + ln15;
        float b1v = b1[col], w2v = W2[col];
#pragma unroll
        for (int r = 0; r < 4; ++r) {
            float v0 = fmaxf(c0[r] + b1v, 0.0f);
            float v1 = fmaxf(c1[r] + b1v, 0.0f);
            d0[r] = fmaf(v0, w2v, d0[r]);
            d1[r] = fmaf(v1, w2v, d1[r]);
        }
    }
    // reduce over the 16 hidden-col lanes (xor 1,2,4,8 stays within quad group)
#pragma unroll
    for (int o = 1; o < 16; o <<= 1) {
#pragma unroll
        for (int r = 0; r < 4; ++r) {
            d0[r] += __shfl_xor(d0[r], o, 64);
            d1[r] += __shfl_xor(d1[r], o, 64);
        }
    }
    if (ln15 == 0) {
#pragma unroll
        for (int r = 0; r < 4; ++r) {
            sDot[wv * 32 + quad * 4 + r]      = d0[r];
            sDot[wv * 32 + 16 + quad * 4 + r] = d1[r];
        }
    }
    __syncthreads();
    if (tid < 128) {
        int e = blockIdx.x * 128 + tid;
        float x = sDot[tid] + b2[0];
        float sp = (x > 20.0f) ? x : log1pf(expf(x));
        float w = sp + 1e-4f;
        ew[e] = w;
        int c = ei[E + e];
        atomicAdd(&deg[c], w);
        atomicAdd(&cnt[c], 1);
    }
}

// ---------------------------------------------------------------- prefix scan (3-kernel) over cnt -> rowptr
__global__ __launch_bounds__(256) void k_scan1(const int* __restrict__ cnt, int* __restrict__ rp,
                                               int* __restrict__ bsum, int n) {
    __shared__ int s[256];
    int t = threadIdx.x, i = blockIdx.x * 256 + t;
    int v = (i < n) ? cnt[i] : 0;
    s[t] = v; __syncthreads();
    for (int o = 1; o < 256; o <<= 1) {
        int x = (t >= o) ? s[t - o] : 0;
        __syncthreads();
        s[t] += x;
        __syncthreads();
    }
    if (i < n) rp[i] = s[t] - v;          // exclusive within block
    if (t == 255) bsum[blockIdx.x] = s[255];
}

__global__ __launch_bounds__(512) void k_scan2(int* __restrict__ bsum, int nb) {
    __shared__ int s[512];
    int t = threadIdx.x;
    int v = (t < nb) ? bsum[t] : 0;
    s[t] = v; __syncthreads();
    for (int o = 1; o < 512; o <<= 1) {
        int x = (t >= o) ? s[t - o] : 0;
        __syncthreads();
        s[t] += x;
        __syncthreads();
    }
    if (t < nb) bsum[t] = s[t] - v;       // exclusive block offsets
}

__global__ __launch_bounds__(256) void k_scan3(int* __restrict__ rp, const int* __restrict__ bsum,
                                               int* __restrict__ cursor, int n, int total) {
    int i = blockIdx.x * 256 + threadIdx.x;
    if (i < n) {
        int r = rp[i] + bsum[blockIdx.x];
        rp[i] = r;
        cursor[i] = r;
    }
    if (i == 0) rp[n] = total;
}

// ---------------------------------------------------------------- dis = rsqrt(deg) in place
__global__ __launch_bounds__(256) void k_rsqrt(float* __restrict__ d, int n) {
    int i = blockIdx.x * 256 + threadIdx.x;
    if (i < n) d[i] = rsqrtf(d[i]);       // deg >= 1 always
}

// ---------------------------------------------------------------- scatter edges into CSR (by dst), norm packed with src
__global__ __launch_bounds__(256) void k_fill(const int* __restrict__ ei, const float* __restrict__ ew,
                                              const float* __restrict__ dis, int* __restrict__ cursor,
                                              int2* __restrict__ epack, int E) {
    int e = blockIdx.x * 256 + threadIdx.x;
    if (e >= E) return;
    int r = ei[e], c = ei[E + e];
    float wn = dis[r] * ew[e] * dis[c];
    int p = atomicAdd(&cursor[c], 1);
    epack[p] = make_int2(r, __float_as_int(wn));
}

// ---------------------------------------------------------------- bf16 MFMA GEMM, LDS-free: C[M,128] = A[M,K]@Bt^T (+bias)
__global__ __launch_bounds__(256) void k_gemm_bf16(
    const __bf16* __restrict__ A, const __bf16* __restrict__ Bt,
    const float* __restrict__ bias, __bf16* __restrict__ C, int M, int K)
{
    int tid = threadIdx.x;
    int wv = tid >> 6, lane = tid & 63;
    int ln15 = lane & 15, quad = lane >> 4;
    int m0 = blockIdx.x * 64;
    int n0 = wv * 32;
    f32x4 acc[4][2];
#pragma unroll
    for (int mt = 0; mt < 4; ++mt)
#pragma unroll
        for (int nt = 0; nt < 2; ++nt) acc[mt][nt] = (f32x4){0.f, 0.f, 0.f, 0.f};

    int rowm[4];
#pragma unroll
    for (int mt = 0; mt < 4; ++mt) {
        int r = m0 + mt * 16 + ln15;
        rowm[mt] = r < M ? r : M - 1;
    }
    for (int kc = 0; kc < K; kc += 32) {
        bf16x8 af[4], bfr[2];
#pragma unroll
        for (int mt = 0; mt < 4; ++mt)
            af[mt] = *(const bf16x8*)&A[(size_t)rowm[mt] * K + kc + quad * 8];
#pragma unroll
        for (int nt = 0; nt < 2; ++nt)
            bfr[nt] = *(const bf16x8*)&Bt[(size_t)(n0 + nt * 16 + ln15) * K + kc + quad * 8];
#pragma unroll
        for (int mt = 0; mt < 4; ++mt)
#pragma unroll
            for (int nt = 0; nt < 2; ++nt)
                acc[mt][nt] = __builtin_amdgcn_mfma_f32_16x16x32_bf16(af[mt], bfr[nt], acc[mt][nt], 0, 0, 0);
    }
#pragma unroll
    for (int nt = 0; nt < 2; ++nt) {
        int col = n0 + nt * 16 + ln15;
        float bv = bias ? bias[col] : 0.0f;
#pragma unroll
        for (int mt = 0; mt < 4; ++mt) {
#pragma unroll
            for (int r = 0; r < 4; ++r) {
                int row = m0 + mt * 16 + quad * 4 + r;
                if (row < M) C[(size_t)row * 128 + col] = (__bf16)(acc[mt][nt][r] + bv);
            }
        }
    }
}

// ---------------------------------------------------------------- aggregate + bias + LN + residual + relu
// one wave per node; packed (src,norm) stream, unroll-8 for MLP
__global__ __launch_bounds__(256) void k_agg_ln(
    const __bf16* __restrict__ hw, const float* __restrict__ dis,
    const int* __restrict__ rowptr, const int2* __restrict__ epack,
    const float* __restrict__ cb, const float* __restrict__ gam,
    const float* __restrict__ bet, const __bf16* __restrict__ res,
    __bf16* __restrict__ out, int n)
{
    int wv = threadIdx.x >> 6;
    int lane = threadIdx.x & 63;
    int i = blockIdx.x * 4 + wv;
    if (i >= n) return;
    float di = dis[i];
    float sn = di * di;                       // self-loop norm = 1/deg
    bf16x2 h2 = *(const bf16x2*)&hw[(size_t)i * HH + lane * 2];
    float2 acc = make_float2((float)h2.x * sn, (float)h2.y * sn);
    int p = rowptr[i], p1 = rowptr[i + 1];
    for (; p + 8 <= p1; p += 8) {
        int2 e[8]; bf16x2 v[8];
#pragma unroll
        for (int k = 0; k < 8; ++k) e[k] = epack[p + k];
#pragma unroll
        for (int k = 0; k < 8; ++k) v[k] = *(const bf16x2*)&hw[(size_t)e[k].x * HH + lane * 2];
#pragma unroll
        for (int k = 0; k < 8; ++k) {
            float wn = __int_as_float(e[k].y);
            acc.x = fmaf((float)v[k].x, wn, acc.x);
            acc.y = fmaf((float)v[k].y, wn, acc.y);
        }
    }
    for (; p < p1; ++p) {
        int2 e = epack[p];
        float wn = __int_as_float(e.y);
        bf16x2 v2 = *(const bf16x2*)&hw[(size_t)e.x * HH + lane * 2];
        acc.x = fmaf((float)v2.x, wn, acc.x);
        acc.y = fmaf((float)v2.y, wn, acc.y);
    }
    float2 cbv = *(const float2*)&cb[lane * 2];
    acc.x += cbv.x; acc.y += cbv.y;
    // LayerNorm over 128 via wave reduction
    float s1 = acc.x + acc.y;
    float s2 = acc.x * acc.x + acc.y * acc.y;
#pragma unroll
    for (int o = 32; o > 0; o >>= 1) {
        s1 += __shfl_xor(s1, o, 64);
        s2 += __shfl_xor(s2, o, 64);
    }
    float mean = s1 * (1.0f / HH);
    float var = fmaxf(s2 * (1.0f / HH) - mean * mean, 0.0f);
    float rstd = rsqrtf(var + 1e-5f);
    float2 gv = *(const float2*)&gam[lane * 2];
    float2 bv = *(const float2*)&bet[lane * 2];
    bf16x2 r2 = *(const bf16x2*)&res[(size_t)i * HH + lane * 2];
    float hx = fmaxf(fmaf(gv.x, (acc.x - mean) * rstd, bv.x) + (float)r2.x, 0.0f);
    float hy = fmaxf(fmaf(gv.y, (acc.y - mean) * rstd, bv.y) + (float)r2.y, 0.0f);
    bf16x2 o2; o2.x = (__bf16)hx; o2.y = (__bf16)hy;
    *(bf16x2*)&out[(size_t)i * HH + lane * 2] = o2;
}

// ---------------------------------------------------------------- mean/max pool per graph over (l0+l1+l2+l3)/4
__global__ __launch_bounds__(128) void k_pool(
    const __bf16* __restrict__ l0, const __bf16* __restrict__ l1,
    const __bf16* __restrict__ l2, const __bf16* __restrict__ l3,
    const int* __restrict__ batch, float* __restrict__ gbuf, int n)
{
    int g = blockIdx.x, t = threadIdx.x;
    int lo = 0, hi = n;
    while (lo < hi) { int m = (lo + hi) >> 1; if (batch[m] < g) lo = m + 1; else hi = m; }
    int start = lo;
    lo = start; hi = n;
    while (lo < hi) { int m = (lo + hi) >> 1; if (batch[m] < g + 1) lo = m + 1; else hi = m; }
    int end = lo;
    float sum = 0.0f, mx = -INFINITY;
    for (int nd = start; nd < end; ++nd) {
        size_t off = (size_t)nd * HH + t;
        float v = ((float)l0[off] + (float)l1[off] + (float)l2[off] + (float)l3[off]) * 0.25f;
        sum += v;
        mx = fmaxf(mx, v);
    }
    int cntg = end - start;
    float mean = sum / fmaxf((float)cntg, 1.0f);
    gbuf[(size_t)g * 256 + t] = mean;
    gbuf[(size_t)g * 256 + 128 + t] = (cntg > 0) ? mx : 0.0f;
}

// ---------------------------------------------------------------- head: relu(g@hW1+hb1)@hW2+hb2
__global__ __launch_bounds__(128) void k_head(const float* __restrict__ gbuf,
                                              const float* __restrict__ hW1, const float* __restrict__ hb1,
                                              const float* __restrict__ hW2, const float* __restrict__ hb2,
                                              float* __restrict__ out) {
    __shared__ __align__(16) float sg[256];
    __shared__ __align__(16) float sh[128];
    int g = blockIdx.x, t = threadIdx.x;
    sg[t] = gbuf[(size_t)g * 256 + t];
    sg[t + 128] = gbuf[(size_t)g * 256 + 128 + t];
    __syncthreads();
    float h = hb1[t];
    for (int k = 0; k < 256; ++k) h = fmaf(sg[k], hW1[(size_t)k * 128 + t], h);
    sh[t] = fmaxf(h, 0.0f);
    __syncthreads();
    if (t < 100) {
        float o = hb2[t];
        for (int k = 0; k < 128; ++k) o = fmaf(sh[k], hW2[(size_t)k * 100 + t], o);
        out[(size_t)g * 100 + t] = o;
    }
}

// ---------------------------------------------------------------- launch
extern "C" void kernel_launch(void* const* d_in, const int* in_sizes, int n_in,
                              void* d_out, int out_size, void* d_ws, size_t ws_size,
                              hipStream_t stream) {
    const float* x     = (const float*)d_in[0];
    const int*   ei    = (const int*)d_in[1];
    const int*   batch = (const int*)d_in[2];
    const float* ea    = (const float*)d_in[3];
    const float* eeW1  = (const float*)d_in[4];
    const float* eeb1  = (const float*)d_in[5];
    const float* eeW2  = (const float*)d_in[6];
    const float* eeb2  = (const float*)d_in[7];
    const float* W[4]  = {(const float*)d_in[8], (const float*)d_in[10], (const float*)d_in[12], (const float*)d_in[14]};
    const float* cb[4] = {(const float*)d_in[9], (const float*)d_in[11], (const float*)d_in[13], (const float*)d_in[15]};
    const float* gm[4] = {(const float*)d_in[16], (const float*)d_in[18], (const float*)d_in[20], (const float*)d_in[22]};
    const float* be[4] = {(const float*)d_in[17], (const float*)d_in[19], (const float*)d_in[21], (const float*)d_in[23]};
    const float* resW  = (const float*)d_in[24];
    const float* resb  = (const float*)d_in[25];
    const float* hW1   = (const float*)d_in[26];
    const float* hb1   = (const float*)d_in[27];
    const float* hW2   = (const float*)d_in[28];
    const float* hb2   = (const float*)d_in[29];
    float* out = (float*)d_out;

    // workspace layout (~195 MB total)
    char* w = (char*)d_ws;
    auto alloc = [&](size_t bytes) { void* p = w; w += (bytes + 255) & ~(size_t)255; return p; };
    float*  ew     = (float*) alloc((size_t)EE * 4);          //  6.4 MB
    float*  dis    = (float*) alloc((size_t)NN * 4);          //  0.4 MB
    int*    cnt    = (int*)   alloc((size_t)NN * 4);          //  0.4 MB (reused as cursor)
    int*    rowptr = (int*)   alloc((size_t)(NN + 1) * 4);    //  0.4 MB
    int*    bsum   = (int*)   alloc(2048);
    int2*   epack  = (int2*)  alloc((size_t)EE * 8);          // 12.8 MB (src, norm)
    __bf16* xb     = (__bf16*)alloc((size_t)NN * INC * 2);    // 19.2 MB
    __bf16* hw     = (__bf16*)alloc((size_t)NN * HH * 2);     // 25.6 MB
    __bf16* res0   = (__bf16*)alloc((size_t)NN * HH * 2);     // 25.6 MB
    __bf16* lout[4];
    for (int i = 0; i < 4; ++i) lout[i] = (__bf16*)alloc((size_t)NN * HH * 2);  // 4 x 25.6 MB
    float*  gbuf   = (float*) alloc((size_t)GB * 256 * 4);    //  0.5 MB
    __bf16* wt0    = (__bf16*)alloc((size_t)INC * HH * 2);
    __bf16* wtR    = (__bf16*)alloc((size_t)INC * HH * 2);
    __bf16* wt1    = (__bf16*)alloc((size_t)HH * HH * 2);
    __bf16* wt2    = (__bf16*)alloc((size_t)HH * HH * 2);
    __bf16* wt3    = (__bf16*)alloc((size_t)HH * HH * 2);
    __bf16* w1f    = (__bf16*)alloc((size_t)8 * 64 * 8 * 2);  // 8 KB MFMA B-frags for edge MLP
    __bf16* wtc[4] = {wt0, wt1, wt2, wt3};
    int*    cursor = cnt;   // cnt dead after scan1

    int nblkN = (NN + 255) / 256;            // 391
    int nblkE = (EE + 255) / 256;            // 6250
    int nblkEdge = EE / 128;                 // 12500 (E divisible by 128)
    int nblkGemm = (NN + 63) / 64;           // 1563
    int nblkCast = (NN * INC / 4 + 255) / 256;
    int nblkT96 = (INC * 128 + 255) / 256;   // 48
    int nblkT128 = (HH * 128 + 255) / 256;   // 64

    k_init<<<nblkN, 256, 0, stream>>>(dis, cnt, NN);
    k_cast<<<nblkCast, 256, 0, stream>>>(x, xb, NN * INC / 4);
    k_castT<<<nblkT96, 256, 0, stream>>>(W[0], wt0, INC);
    k_castT<<<nblkT96, 256, 0, stream>>>(resW, wtR, INC);
    k_castT<<<nblkT128, 256, 0, stream>>>(W[1], wt1, HH);
    k_castT<<<nblkT128, 256, 0, stream>>>(W[2], wt2, HH);
    k_castT<<<nblkT128, 256, 0, stream>>>(W[3], wt3, HH);
    k_prep_w1<<<1, 512, 0, stream>>>(eeW1, w1f);
    k_edge_mlp_mfma<<<nblkEdge, 256, 0, stream>>>(ea, ei, w1f, eeb1, eeW2, eeb2, ew, dis, cnt, EE);
    k_scan1<<<nblkN, 256, 0, stream>>>(cnt, rowptr, bsum, NN);
    k_scan2<<<1, 512, 0, stream>>>(bsum, nblkN);
    k_scan3<<<nblkN, 256, 0, stream>>>(rowptr, bsum, cursor, NN, EE);
    k_rsqrt<<<nblkN, 256, 0, stream>>>(dis, NN);
    k_fill<<<nblkE, 256, 0, stream>>>(ei, ew, dis, cursor, epack, EE);

    // layer 0 (K=96): hw = x@W0; res0 = x@res_W + res_b
    k_gemm_bf16<<<nblkGemm, 256, 0, stream>>>(xb, wt0, nullptr, hw, NN, INC);
    k_gemm_bf16<<<nblkGemm, 256, 0, stream>>>(xb, wtR, resb, res0, NN, INC);
    k_agg_ln<<<(NN + 3) / 4, 256, 0, stream>>>(hw, dis, rowptr, epack,
                                               cb[0], gm[0], be[0], res0, lout[0], NN);
    // layers 1..3
    for (int l = 1; l < 4; ++l) {
        k_gemm_bf16<<<nblkGemm, 256, 0, stream>>>(lout[l - 1], wtc[l], nullptr, hw, NN, HH);
        k_agg_ln<<<(NN + 3) / 4, 256, 0, stream>>>(hw, dis, rowptr, epack,
                                                   cb[l], gm[l], be[l], lout[l - 1], lout[l], NN);
    }

    k_pool<<<GB, 128, 0, stream>>>(lout[0], lout[1], lout[2], lout[3], batch, gbuf, NN);
    k_head<<<GB, 128, 0, stream>>>(gbuf, hW1, hb1, hW2, hb2, out);
}